// Round 2
// baseline (2034.314 us; speedup 1.0000x reference)
//
#include <hip/hip_runtime.h>
#include <stdint.h>

#pragma clang fp contract(off)

typedef unsigned long long u64;

#define NBATCH 16
#define NPTS   4096
#define NCH    64
#define NPOINT 1024
#define NSAMP  32

// ---- workspace byte offsets ----
#define OFF_FEATT   0u          // 16*4096*64*4 = 16777216
#define OFF_NEWXYZ  16777216u   // 16*1024*3*4 = 196608
#define OFF_GIDX    16973824u   // 16*1024*32*4 = 2097152
#define OFF_WT0     19070976u   // 67*64*4 = 17152
#define OFF_BP0     19088128u   // 64*4 (pad 256)
#define OFF_WT1     19088384u   // 64*64*4 = 16384
#define OFF_BP1     19104768u   // pad 256
#define OFF_WT2     19105024u   // 64*128*4 = 32768
#define OFF_BP2     19137792u   // pad 512
#define WS_NEED     19138304u

// Monotone map: float bits -> unsigned preserving total order (neg < pos).
__device__ __forceinline__ unsigned fkey(float f) {
  unsigned b = __float_as_uint(f);
  unsigned mask = ((unsigned)((int)b >> 31)) | 0x80000000u;
  return b ^ mask;
}

// ---------------------------------------------------------------------------
// Fold BN (eval) into conv weights/bias; transpose W to [c][o].
// ---------------------------------------------------------------------------
__global__ __launch_bounds__(256) void prep_kernel(
    const float* __restrict__ W0, const float* __restrict__ b0, const float* __restrict__ g0,
    const float* __restrict__ be0, const float* __restrict__ m0, const float* __restrict__ v0,
    const float* __restrict__ W1, const float* __restrict__ b1, const float* __restrict__ g1,
    const float* __restrict__ be1, const float* __restrict__ m1, const float* __restrict__ v1,
    const float* __restrict__ W2, const float* __restrict__ b2, const float* __restrict__ g2,
    const float* __restrict__ be2, const float* __restrict__ m2, const float* __restrict__ v2,
    float* __restrict__ wt0, float* __restrict__ bp0,
    float* __restrict__ wt1, float* __restrict__ bp1,
    float* __restrict__ wt2, float* __restrict__ bp2) {
  int t = threadIdx.x;
  for (int i = t; i < 64 * 67; i += 256) {
    int o = i / 67, c = i % 67;
    float s = g0[o] / sqrtf(v0[o] + 1e-5f);
    wt0[c * 64 + o] = W0[o * 67 + c] * s;
  }
  for (int o = t; o < 64; o += 256) {
    float s = g0[o] / sqrtf(v0[o] + 1e-5f);
    bp0[o] = (b0[o] - m0[o]) * s + be0[o];
  }
  for (int i = t; i < 64 * 64; i += 256) {
    int o = i / 64, c = i % 64;
    float s = g1[o] / sqrtf(v1[o] + 1e-5f);
    wt1[c * 64 + o] = W1[o * 64 + c] * s;
  }
  for (int o = t; o < 64; o += 256) {
    float s = g1[o] / sqrtf(v1[o] + 1e-5f);
    bp1[o] = (b1[o] - m1[o]) * s + be1[o];
  }
  for (int i = t; i < 128 * 64; i += 256) {
    int o = i / 64, c = i % 64;
    float s = g2[o] / sqrtf(v2[o] + 1e-5f);
    wt2[c * 128 + o] = W2[o * 64 + c] * s;
  }
  for (int o = t; o < 128; o += 256) {
    float s = g2[o] / sqrtf(v2[o] + 1e-5f);
    bp2[o] = (b2[o] - m2[o]) * s + be2[o];
  }
}

// ---------------------------------------------------------------------------
// features [B,C,N] -> featT [B,N,C]  (tiled 32x32 transpose)
// ---------------------------------------------------------------------------
__global__ __launch_bounds__(256) void transpose_kernel(const float* __restrict__ feat,
                                                        float* __restrict__ featT) {
  __shared__ float tile[32][33];
  int b = blockIdx.z;
  int n0 = blockIdx.x * 32;
  int c0 = blockIdx.y * 32;
  int tx = threadIdx.x, ty = threadIdx.y;  // 32 x 8
#pragma unroll
  for (int j = 0; j < 4; ++j)
    tile[ty + 8 * j][tx] = feat[b * (NCH * NPTS) + (c0 + ty + 8 * j) * NPTS + n0 + tx];
  __syncthreads();
#pragma unroll
  for (int j = 0; j < 4; ++j)
    featT[b * (NPTS * NCH) + (size_t)(n0 + ty + 8 * j) * NCH + c0 + tx] = tile[tx][ty + 8 * j];
}

// ---------------------------------------------------------------------------
// Exact farthest-point sampling. One block per batch, 256 threads x 16 pts.
// ---------------------------------------------------------------------------
__global__ __launch_bounds__(256) void fps_kernel(const float* __restrict__ xyz,
                                                  float* __restrict__ nxyz,
                                                  float* __restrict__ out_xyz) {
  __shared__ float sx[NPTS], sy[NPTS], sz[NPTS];
  __shared__ int sidx[NPOINT];
  __shared__ float rv[2][4];
  __shared__ int rp[2][4];
  int b = blockIdx.x;
  int t = threadIdx.x;
  const float* X = xyz + (size_t)b * NPTS * 3;

  float qx[16], qy[16], qz[16], d[16];
#pragma unroll
  for (int i = 0; i < 16; ++i) {
    int p = t + 256 * i;
    float x = X[p * 3 + 0], y = X[p * 3 + 1], z = X[p * 3 + 2];
    qx[i] = x; qy[i] = y; qz[i] = z;
    sx[p] = x; sy[p] = y; sz[p] = z;
    d[i] = 1e10f;
  }
  if (t == 0) sidx[0] = 0;
  __syncthreads();

  int last = 0;
  for (int k = 1; k < NPOINT; ++k) {
    float lx = sx[last], ly = sy[last], lz = sz[last];
    float bv = -1.0f;
    int bp = 0x7fffffff;
#pragma unroll
    for (int i = 0; i < 16; ++i) {
      float dx = qx[i] - lx, dy = qy[i] - ly, dz = qz[i] - lz;
      float dist = (dx * dx + dy * dy) + dz * dz;  // contract(off): exact order
      float nd = fminf(d[i], dist);
      d[i] = nd;
      if (nd > bv) { bv = nd; bp = t + 256 * i; }  // ascending p: ties keep first
    }
#pragma unroll
    for (int off = 32; off >= 1; off >>= 1) {
      float ov = __shfl_down(bv, (unsigned)off, 64);
      int op = __shfl_down(bp, (unsigned)off, 64);
      if (ov > bv || (ov == bv && op < bp)) { bv = ov; bp = op; }
    }
    int kb = k & 1;
    if ((t & 63) == 0) { rv[kb][t >> 6] = bv; rp[kb][t >> 6] = bp; }
    __syncthreads();
    float wv = rv[kb][0];
    int wp = rp[kb][0];
#pragma unroll
    for (int wq = 1; wq < 4; ++wq) {
      float v2 = rv[kb][wq]; int p2 = rp[kb][wq];
      if (v2 > wv || (v2 == wv && p2 < wp)) { wv = v2; wp = p2; }
    }
    last = wp;
    if (t == 0) sidx[k] = wp;
  }
  __syncthreads();
  for (int p = t; p < NPOINT; p += 256) {
    int g = sidx[p];
    int o = (b * NPOINT + p) * 3;
    float x = sx[g], y = sy[g], z = sz[g];
    nxyz[o] = x; nxyz[o + 1] = y; nxyz[o + 2] = z;
    out_xyz[o] = x; out_xyz[o + 1] = y; out_xyz[o + 2] = z;
  }
}

// ---------------------------------------------------------------------------
// 32 nearest neighbors per sampled point. One block per (b,p), 256 thr x 16.
// Keys use the sign-corrected monotone float->uint map (sq can round NEGATIVE
// for the self point; raw-bits unsigned compare sorted those LAST -> wrong
// neighbor set; reference sorts them FIRST).
// ---------------------------------------------------------------------------
__global__ __launch_bounds__(256) void topk_kernel(const float* __restrict__ xyz,
                                                   const float* __restrict__ nxyz,
                                                   int* __restrict__ gidx) {
  __shared__ u64 tr[512];
  int blk = blockIdx.x;  // b*1024 + p
  int b = blk >> 10;
  int t = threadIdx.x;
  const float* X = xyz + (size_t)b * NPTS * 3;
  float px = nxyz[blk * 3 + 0], py = nxyz[blk * 3 + 1], pz = nxyz[blk * 3 + 2];
  float n2p = (px * px + py * py) + pz * pz;

  float dq[16];
#pragma unroll
  for (int i = 0; i < 16; ++i) {
    int n = t + 256 * i;
    float x = X[n * 3 + 0], y = X[n * 3 + 1], z = X[n * 3 + 2];
    float n2x = (x * x + y * y) + z * z;
    float dot = fmaf(pz, z, fmaf(py, y, px * x));
    dq[i] = (n2p + n2x) - 2.0f * dot;
  }
  float mv = dq[0];
  int mp = t;
#pragma unroll
  for (int i = 1; i < 16; ++i) {
    if (dq[i] < mv) { mv = dq[i]; mp = t + 256 * i; }
  }
  tr[256 + t] = ((u64)fkey(mv) << 32) | (unsigned)mp;
  __syncthreads();
  for (int lvl = 128; lvl >= 1; lvl >>= 1) {
    if (t < lvl) {
      u64 a = tr[2 * (lvl + t)], c = tr[2 * (lvl + t) + 1];
      tr[lvl + t] = a < c ? a : c;
    }
    __syncthreads();
  }
  int* go = gidx + (size_t)blk * NSAMP;
  for (int k = 0; k < NSAMP; ++k) {
    u64 root = tr[1];
    int wp = (int)(root & 0xffffffffull);
    if (t == 0) go[k] = wp;
    __syncthreads();  // everyone read root before owner mutates the tree
    if ((wp & 255) == t) {
      int slot = wp >> 8;
#pragma unroll
      for (int i = 0; i < 16; ++i)
        if (i == slot) dq[i] = __int_as_float(0x7f800000);
      float nv = dq[0];
      int np2 = t;
#pragma unroll
      for (int i = 1; i < 16; ++i) {
        if (dq[i] < nv) { nv = dq[i]; np2 = t + 256 * i; }
      }
      int nd = 256 + t;
      tr[nd] = ((u64)fkey(nv) << 32) | (unsigned)np2;
      nd >>= 1;
      while (nd >= 1) {
        u64 a = tr[2 * nd], c = tr[2 * nd + 1];
        tr[nd] = a < c ? a : c;
        nd >>= 1;
      }
    }
    __syncthreads();
  }
}

// ---------------------------------------------------------------------------
// Gather + 3-layer pointwise MLP (BN folded) + max over 32 samples.
// ---------------------------------------------------------------------------
__global__ __launch_bounds__(256) void mlp_kernel(
    const float* __restrict__ xyz, const float* __restrict__ featT,
    const float* __restrict__ nxyz, const int* __restrict__ gidx,
    const float* __restrict__ wt0, const float* __restrict__ bp0,
    const float* __restrict__ wt1, const float* __restrict__ bp1,
    const float* __restrict__ wt2, const float* __restrict__ bp2,
    float* __restrict__ outF) {
  __shared__ float XA[2][32][69];
  __shared__ float XB[2][32][69];
  int blk = blockIdx.x;
  int b = blk >> 9;
  int pb = (blk & 511) << 1;
  int t = threadIdx.x;

  for (int u = t; u < 2 * 32 * 67; u += 256) {
    int pt = u / (32 * 67);
    int r = u - pt * (32 * 67);
    int s = r / 67;
    int c = r - s * 67;
    int pp = pb + pt;
    int g = gidx[(size_t)(b * NPOINT + pp) * NSAMP + s];
    float val;
    if (c < 3)
      val = xyz[(size_t)(b * NPTS + g) * 3 + c] - nxyz[(size_t)(b * NPOINT + pp) * 3 + c];
    else
      val = featT[(size_t)(b * NPTS + g) * NCH + (c - 3)];
    XA[pt][s][c] = val;
  }
  __syncthreads();

  int w = __builtin_amdgcn_readfirstlane((int)(threadIdx.x >> 6));
  int l = t & 63;
  int s = l & 31;
  int pt = l >> 5;

  {  // L0: XA[*,*,0:67] -> XB[*,*,0:64]
    int ob = w * 16;
    float acc[16];
#pragma unroll
    for (int j = 0; j < 16; ++j) acc[j] = bp0[ob + j];
    for (int c = 0; c < 67; ++c) {
      float xv = XA[pt][s][c];
      const float* wr = wt0 + c * 64 + ob;
#pragma unroll
      for (int j = 0; j < 16; ++j) acc[j] = fmaf(xv, wr[j], acc[j]);
    }
#pragma unroll
    for (int j = 0; j < 16; ++j) XB[pt][s][ob + j] = fmaxf(acc[j], 0.0f);
  }
  __syncthreads();

  {  // L1: XB -> XA[*,*,0:64]
    int ob = w * 16;
    float acc[16];
#pragma unroll
    for (int j = 0; j < 16; ++j) acc[j] = bp1[ob + j];
    for (int c = 0; c < 64; ++c) {
      float xv = XB[pt][s][c];
      const float* wr = wt1 + c * 64 + ob;
#pragma unroll
      for (int j = 0; j < 16; ++j) acc[j] = fmaf(xv, wr[j], acc[j]);
    }
#pragma unroll
    for (int j = 0; j < 16; ++j) XA[pt][s][ob + j] = fmaxf(acc[j], 0.0f);
  }
  __syncthreads();

  {  // L2: XA -> regs; ReLU; butterfly max over the 32 s-lanes; write out
    int ob = w * 32;
    float acc[32];
#pragma unroll
    for (int j = 0; j < 32; ++j) acc[j] = bp2[ob + j];
    for (int c = 0; c < 64; ++c) {
      float xv = XA[pt][s][c];
      const float* wr = wt2 + c * 128 + ob;
#pragma unroll
      for (int j = 0; j < 32; ++j) acc[j] = fmaf(xv, wr[j], acc[j]);
    }
    float* orow = outF + (size_t)(b * NPOINT + pb + pt) * 128 + ob;
#pragma unroll
    for (int j = 0; j < 32; ++j) {
      float m = fmaxf(acc[j], 0.0f);
#pragma unroll
      for (int off = 16; off >= 1; off >>= 1) m = fmaxf(m, __shfl_xor(m, off, 64));
      if (s == 0) orow[j] = m;
    }
  }
}

// ---------------------------------------------------------------------------
extern "C" void kernel_launch(void* const* d_in, const int* in_sizes, int n_in,
                              void* d_out, int out_size, void* d_ws, size_t ws_size,
                              hipStream_t stream) {
  if (n_in < 20 || ws_size < WS_NEED) return;
  const float* xyz = (const float*)d_in[0];
  const float* feat = (const float*)d_in[1];
  const float* W0 = (const float*)d_in[2];
  const float* b0 = (const float*)d_in[3];
  const float* g0 = (const float*)d_in[4];
  const float* be0 = (const float*)d_in[5];
  const float* m0 = (const float*)d_in[6];
  const float* v0 = (const float*)d_in[7];
  const float* W1 = (const float*)d_in[8];
  const float* b1 = (const float*)d_in[9];
  const float* g1 = (const float*)d_in[10];
  const float* be1 = (const float*)d_in[11];
  const float* m1 = (const float*)d_in[12];
  const float* v1 = (const float*)d_in[13];
  const float* W2 = (const float*)d_in[14];
  const float* b2 = (const float*)d_in[15];
  const float* g2 = (const float*)d_in[16];
  const float* be2 = (const float*)d_in[17];
  const float* m2 = (const float*)d_in[18];
  const float* v2 = (const float*)d_in[19];

  char* ws = (char*)d_ws;
  float* featT = (float*)(ws + OFF_FEATT);
  float* nxyz = (float*)(ws + OFF_NEWXYZ);
  int* gidx = (int*)(ws + OFF_GIDX);
  float* wt0 = (float*)(ws + OFF_WT0);
  float* bp0 = (float*)(ws + OFF_BP0);
  float* wt1 = (float*)(ws + OFF_WT1);
  float* bp1 = (float*)(ws + OFF_BP1);
  float* wt2 = (float*)(ws + OFF_WT2);
  float* bp2 = (float*)(ws + OFF_BP2);

  float* out_xyz = (float*)d_out;                         // [16,1024,3]
  float* out_feat = (float*)d_out + NBATCH * NPOINT * 3;  // [16,1024,128]

  hipLaunchKernelGGL(prep_kernel, dim3(1), dim3(256), 0, stream,
                     W0, b0, g0, be0, m0, v0, W1, b1, g1, be1, m1, v1,
                     W2, b2, g2, be2, m2, v2, wt0, bp0, wt1, bp1, wt2, bp2);
  hipLaunchKernelGGL(transpose_kernel, dim3(NPTS / 32, NCH / 32, NBATCH), dim3(32, 8), 0, stream,
                     feat, featT);
  hipLaunchKernelGGL(fps_kernel, dim3(NBATCH), dim3(256), 0, stream, xyz, nxyz, out_xyz);
  hipLaunchKernelGGL(topk_kernel, dim3(NBATCH * NPOINT), dim3(256), 0, stream, xyz, nxyz, gidx);
  hipLaunchKernelGGL(mlp_kernel, dim3(NBATCH * NPOINT / 2), dim3(256), 0, stream,
                     xyz, featT, nxyz, gidx, wt0, bp0, wt1, bp1, wt2, bp2, out_feat);
}

// Round 3
// 1779.188 us; speedup vs baseline: 1.1434x; 1.1434x over previous
//
#include <hip/hip_runtime.h>
#include <stdint.h>

#pragma clang fp contract(off)

typedef unsigned long long u64;

#define NBATCH 16
#define NPTS   4096
#define NCH    64
#define NPOINT 1024
#define NSAMP  32

// ---- workspace byte offsets ----
#define OFF_FEATT   0u          // 16*4096*64*4 = 16777216
#define OFF_NEWXYZ  16777216u   // 16*1024*3*4 = 196608
#define OFF_GIDX    16973824u   // 16*1024*32*4 = 2097152
#define OFF_WT0     19070976u   // 67*64*4 = 17152
#define OFF_BP0     19088128u   // 64*4 (pad 256)
#define OFF_WT1     19088384u   // 64*64*4 = 16384
#define OFF_BP1     19104768u   // pad 256
#define OFF_WT2     19105024u   // 64*128*4 = 32768
#define OFF_BP2     19137792u   // pad 512
#define WS_NEED     19138304u

// Monotone map: float bits -> unsigned preserving total order (neg < pos).
__device__ __forceinline__ unsigned fkey(float f) {
  unsigned b = __float_as_uint(f);
  unsigned mask = ((unsigned)((int)b >> 31)) | 0x80000000u;
  return b ^ mask;
}

// ---------------------------------------------------------------------------
// Fold BN (eval) into conv weights/bias; transpose W to [c][o].
// ---------------------------------------------------------------------------
__global__ __launch_bounds__(256) void prep_kernel(
    const float* __restrict__ W0, const float* __restrict__ b0, const float* __restrict__ g0,
    const float* __restrict__ be0, const float* __restrict__ m0, const float* __restrict__ v0,
    const float* __restrict__ W1, const float* __restrict__ b1, const float* __restrict__ g1,
    const float* __restrict__ be1, const float* __restrict__ m1, const float* __restrict__ v1,
    const float* __restrict__ W2, const float* __restrict__ b2, const float* __restrict__ g2,
    const float* __restrict__ be2, const float* __restrict__ m2, const float* __restrict__ v2,
    float* __restrict__ wt0, float* __restrict__ bp0,
    float* __restrict__ wt1, float* __restrict__ bp1,
    float* __restrict__ wt2, float* __restrict__ bp2) {
  int t = threadIdx.x;
  for (int i = t; i < 64 * 67; i += 256) {
    int o = i / 67, c = i % 67;
    float s = g0[o] / sqrtf(v0[o] + 1e-5f);
    wt0[c * 64 + o] = W0[o * 67 + c] * s;
  }
  for (int o = t; o < 64; o += 256) {
    float s = g0[o] / sqrtf(v0[o] + 1e-5f);
    bp0[o] = (b0[o] - m0[o]) * s + be0[o];
  }
  for (int i = t; i < 64 * 64; i += 256) {
    int o = i / 64, c = i % 64;
    float s = g1[o] / sqrtf(v1[o] + 1e-5f);
    wt1[c * 64 + o] = W1[o * 64 + c] * s;
  }
  for (int o = t; o < 64; o += 256) {
    float s = g1[o] / sqrtf(v1[o] + 1e-5f);
    bp1[o] = (b1[o] - m1[o]) * s + be1[o];
  }
  for (int i = t; i < 128 * 64; i += 256) {
    int o = i / 64, c = i % 64;
    float s = g2[o] / sqrtf(v2[o] + 1e-5f);
    wt2[c * 128 + o] = W2[o * 64 + c] * s;
  }
  for (int o = t; o < 128; o += 256) {
    float s = g2[o] / sqrtf(v2[o] + 1e-5f);
    bp2[o] = (b2[o] - m2[o]) * s + be2[o];
  }
}

// ---------------------------------------------------------------------------
// features [B,C,N] -> featT [B,N,C]  (tiled 32x32 transpose)
// ---------------------------------------------------------------------------
__global__ __launch_bounds__(256) void transpose_kernel(const float* __restrict__ feat,
                                                        float* __restrict__ featT) {
  __shared__ float tile[32][33];
  int b = blockIdx.z;
  int n0 = blockIdx.x * 32;
  int c0 = blockIdx.y * 32;
  int tx = threadIdx.x, ty = threadIdx.y;  // 32 x 8
#pragma unroll
  for (int j = 0; j < 4; ++j)
    tile[ty + 8 * j][tx] = feat[b * (NCH * NPTS) + (c0 + ty + 8 * j) * NPTS + n0 + tx];
  __syncthreads();
#pragma unroll
  for (int j = 0; j < 4; ++j)
    featT[b * (NPTS * NCH) + (size_t)(n0 + ty + 8 * j) * NCH + c0 + tx] = tile[tx][ty + 8 * j];
}

// ---------------------------------------------------------------------------
// Exact farthest-point sampling. One block per batch, 1024 threads x 4 pts.
// Per-iter critical path minimized:
//  - distance update: 4 elems/thread, contract(off), order (dx^2+dy^2)+dz^2
//  - wave argmax: value fmaxf tree + lowest-idx-at-max scan, packed u64 key
//    (valbits<<32 | ~idx), reduced with VALU-speed DPP (no ds_bpermute)
//  - ONE barrier/iter: lane63-of-wave writes key to double-buffered LDS;
//    all threads redundantly max the 16 wave keys (broadcast reads).
// Tie semantics: max value, then min index == jnp.argmax first-occurrence.
// ---------------------------------------------------------------------------
#define DPP_MAXSTEP(CTRL)                                                              \
  do {                                                                                 \
    unsigned lo = (unsigned)key, hi = (unsigned)(key >> 32);                           \
    unsigned slo = (unsigned)__builtin_amdgcn_update_dpp((int)lo, (int)lo, CTRL, 0xF, 0xF, false); \
    unsigned shi = (unsigned)__builtin_amdgcn_update_dpp((int)hi, (int)hi, CTRL, 0xF, 0xF, false); \
    u64 s = ((u64)shi << 32) | slo;                                                    \
    if (s > key) key = s;                                                              \
  } while (0)

__global__ __launch_bounds__(1024) void fps_kernel(const float* __restrict__ xyz,
                                                   float* __restrict__ nxyz,
                                                   float* __restrict__ out_xyz) {
  __shared__ float sx[NPTS], sy[NPTS], sz[NPTS];
  __shared__ int sidx[NPOINT];
  __shared__ u64 wkey[2][16];
  int b = blockIdx.x;
  int t = threadIdx.x;
  const float* X = xyz + (size_t)b * NPTS * 3;

  float qx[4], qy[4], qz[4], d[4];
#pragma unroll
  for (int i = 0; i < 4; ++i) {
    int p = t + 1024 * i;
    float x = X[p * 3 + 0], y = X[p * 3 + 1], z = X[p * 3 + 2];
    qx[i] = x; qy[i] = y; qz[i] = z;
    sx[p] = x; sy[p] = y; sz[p] = z;
    d[i] = 1e10f;
  }
  if (t == 0) sidx[0] = 0;
  __syncthreads();

  int last = 0;
  for (int k = 1; k < NPOINT; ++k) {
    float lx = sx[last], ly = sy[last], lz = sz[last];
#pragma unroll
    for (int i = 0; i < 4; ++i) {
      float dx = qx[i] - lx, dy = qy[i] - ly, dz = qz[i] - lz;
      float dist = (dx * dx + dy * dy) + dz * dz;  // contract(off): exact order
      d[i] = fminf(d[i], dist);
    }
    // local max value (exact fp compare semantics; no NaN, no -0 possible)
    float mv = fmaxf(fmaxf(d[0], d[1]), fmaxf(d[2], d[3]));
    // lowest local index attaining mv (descending scan -> last write = lowest i)
    int mp = t;
#pragma unroll
    for (int i = 3; i >= 0; --i)
      if (d[i] == mv) mp = t + 1024 * i;

    u64 key = ((u64)__float_as_uint(mv) << 32) | (unsigned)(~(unsigned)mp);
    // wave64 max-reduce at VALU speed; lane 63 ends with the wave max
    DPP_MAXSTEP(0xB1);   // quad_perm [1,0,3,2]  (xor 1)
    DPP_MAXSTEP(0x4E);   // quad_perm [2,3,0,1]  (xor 2)
    DPP_MAXSTEP(0x124);  // row_ror:4
    DPP_MAXSTEP(0x128);  // row_ror:8   -> 16-lane rows uniform
    DPP_MAXSTEP(0x142);  // row_bcast15 -> rows 1,3 have pair max
    DPP_MAXSTEP(0x143);  // row_bcast31 -> lanes 32..63 have wave max

    int kb = k & 1;
    if ((t & 63) == 63) wkey[kb][t >> 6] = key;
    __syncthreads();
    // block max over 16 wave keys (broadcast LDS reads, tree reduce)
    u64 w0 = wkey[kb][0], w1 = wkey[kb][1], w2 = wkey[kb][2], w3 = wkey[kb][3];
    u64 w4 = wkey[kb][4], w5 = wkey[kb][5], w6 = wkey[kb][6], w7 = wkey[kb][7];
    u64 w8 = wkey[kb][8], w9 = wkey[kb][9], wa = wkey[kb][10], wb = wkey[kb][11];
    u64 wc = wkey[kb][12], wd = wkey[kb][13], we = wkey[kb][14], wf = wkey[kb][15];
    w0 = w0 > w1 ? w0 : w1;  w2 = w2 > w3 ? w2 : w3;
    w4 = w4 > w5 ? w4 : w5;  w6 = w6 > w7 ? w6 : w7;
    w8 = w8 > w9 ? w8 : w9;  wa = wa > wb ? wa : wb;
    wc = wc > wd ? wc : wd;  we = we > wf ? we : wf;
    w0 = w0 > w2 ? w0 : w2;  w4 = w4 > w6 ? w4 : w6;
    w8 = w8 > wa ? w8 : wa;  wc = wc > we ? wc : we;
    w0 = w0 > w4 ? w0 : w4;  w8 = w8 > wc ? w8 : wc;
    w0 = w0 > w8 ? w0 : w8;
    last = (int)(~(unsigned)w0);
    if (t == 0) sidx[k] = last;
    // no second barrier: wkey double-buffered on k&1
  }
  __syncthreads();
  if (t < NPOINT) {
    int g = sidx[t];
    int o = (b * NPOINT + t) * 3;
    float x = sx[g], y = sy[g], z = sz[g];
    nxyz[o] = x; nxyz[o + 1] = y; nxyz[o + 2] = z;
    out_xyz[o] = x; out_xyz[o + 1] = y; out_xyz[o + 2] = z;
  }
}

// ---------------------------------------------------------------------------
// 32 nearest neighbors per sampled point. One block per (b,p), 256 thr x 16.
// ---------------------------------------------------------------------------
__global__ __launch_bounds__(256) void topk_kernel(const float* __restrict__ xyz,
                                                   const float* __restrict__ nxyz,
                                                   int* __restrict__ gidx) {
  __shared__ u64 tr[512];
  int blk = blockIdx.x;  // b*1024 + p
  int b = blk >> 10;
  int t = threadIdx.x;
  const float* X = xyz + (size_t)b * NPTS * 3;
  float px = nxyz[blk * 3 + 0], py = nxyz[blk * 3 + 1], pz = nxyz[blk * 3 + 2];
  float n2p = (px * px + py * py) + pz * pz;

  float dq[16];
#pragma unroll
  for (int i = 0; i < 16; ++i) {
    int n = t + 256 * i;
    float x = X[n * 3 + 0], y = X[n * 3 + 1], z = X[n * 3 + 2];
    float n2x = (x * x + y * y) + z * z;
    float dot = fmaf(pz, z, fmaf(py, y, px * x));
    dq[i] = (n2p + n2x) - 2.0f * dot;
  }
  float mv = dq[0];
  int mp = t;
#pragma unroll
  for (int i = 1; i < 16; ++i) {
    if (dq[i] < mv) { mv = dq[i]; mp = t + 256 * i; }
  }
  tr[256 + t] = ((u64)fkey(mv) << 32) | (unsigned)mp;
  __syncthreads();
  for (int lvl = 128; lvl >= 1; lvl >>= 1) {
    if (t < lvl) {
      u64 a = tr[2 * (lvl + t)], c = tr[2 * (lvl + t) + 1];
      tr[lvl + t] = a < c ? a : c;
    }
    __syncthreads();
  }
  int* go = gidx + (size_t)blk * NSAMP;
  for (int k = 0; k < NSAMP; ++k) {
    u64 root = tr[1];
    int wp = (int)(root & 0xffffffffull);
    if (t == 0) go[k] = wp;
    __syncthreads();  // everyone read root before owner mutates the tree
    if ((wp & 255) == t) {
      int slot = wp >> 8;
#pragma unroll
      for (int i = 0; i < 16; ++i)
        if (i == slot) dq[i] = __int_as_float(0x7f800000);
      float nv = dq[0];
      int np2 = t;
#pragma unroll
      for (int i = 1; i < 16; ++i) {
        if (dq[i] < nv) { nv = dq[i]; np2 = t + 256 * i; }
      }
      int nd = 256 + t;
      tr[nd] = ((u64)fkey(nv) << 32) | (unsigned)np2;
      nd >>= 1;
      while (nd >= 1) {
        u64 a = tr[2 * nd], c = tr[2 * nd + 1];
        tr[nd] = a < c ? a : c;
        nd >>= 1;
      }
    }
    __syncthreads();
  }
}

// ---------------------------------------------------------------------------
// Gather + 3-layer pointwise MLP (BN folded) + max over 32 samples.
// ---------------------------------------------------------------------------
__global__ __launch_bounds__(256) void mlp_kernel(
    const float* __restrict__ xyz, const float* __restrict__ featT,
    const float* __restrict__ nxyz, const int* __restrict__ gidx,
    const float* __restrict__ wt0, const float* __restrict__ bp0,
    const float* __restrict__ wt1, const float* __restrict__ bp1,
    const float* __restrict__ wt2, const float* __restrict__ bp2,
    float* __restrict__ outF) {
  __shared__ float XA[2][32][69];
  __shared__ float XB[2][32][69];
  int blk = blockIdx.x;
  int b = blk >> 9;
  int pb = (blk & 511) << 1;
  int t = threadIdx.x;

  for (int u = t; u < 2 * 32 * 67; u += 256) {
    int pt = u / (32 * 67);
    int r = u - pt * (32 * 67);
    int s = r / 67;
    int c = r - s * 67;
    int pp = pb + pt;
    int g = gidx[(size_t)(b * NPOINT + pp) * NSAMP + s];
    float val;
    if (c < 3)
      val = xyz[(size_t)(b * NPTS + g) * 3 + c] - nxyz[(size_t)(b * NPOINT + pp) * 3 + c];
    else
      val = featT[(size_t)(b * NPTS + g) * NCH + (c - 3)];
    XA[pt][s][c] = val;
  }
  __syncthreads();

  int w = __builtin_amdgcn_readfirstlane((int)(threadIdx.x >> 6));
  int l = t & 63;
  int s = l & 31;
  int pt = l >> 5;

  {  // L0: XA[*,*,0:67] -> XB[*,*,0:64]
    int ob = w * 16;
    float acc[16];
#pragma unroll
    for (int j = 0; j < 16; ++j) acc[j] = bp0[ob + j];
    for (int c = 0; c < 67; ++c) {
      float xv = XA[pt][s][c];
      const float* wr = wt0 + c * 64 + ob;
#pragma unroll
      for (int j = 0; j < 16; ++j) acc[j] = fmaf(xv, wr[j], acc[j]);
    }
#pragma unroll
    for (int j = 0; j < 16; ++j) XB[pt][s][ob + j] = fmaxf(acc[j], 0.0f);
  }
  __syncthreads();

  {  // L1: XB -> XA[*,*,0:64]
    int ob = w * 16;
    float acc[16];
#pragma unroll
    for (int j = 0; j < 16; ++j) acc[j] = bp1[ob + j];
    for (int c = 0; c < 64; ++c) {
      float xv = XB[pt][s][c];
      const float* wr = wt1 + c * 64 + ob;
#pragma unroll
      for (int j = 0; j < 16; ++j) acc[j] = fmaf(xv, wr[j], acc[j]);
    }
#pragma unroll
    for (int j = 0; j < 16; ++j) XA[pt][s][ob + j] = fmaxf(acc[j], 0.0f);
  }
  __syncthreads();

  {  // L2: XA -> regs; ReLU; butterfly max over the 32 s-lanes; write out
    int ob = w * 32;
    float acc[32];
#pragma unroll
    for (int j = 0; j < 32; ++j) acc[j] = bp2[ob + j];
    for (int c = 0; c < 64; ++c) {
      float xv = XA[pt][s][c];
      const float* wr = wt2 + c * 128 + ob;
#pragma unroll
      for (int j = 0; j < 32; ++j) acc[j] = fmaf(xv, wr[j], acc[j]);
    }
    float* orow = outF + (size_t)(b * NPOINT + pb + pt) * 128 + ob;
#pragma unroll
    for (int j = 0; j < 32; ++j) {
      float m = fmaxf(acc[j], 0.0f);
#pragma unroll
      for (int off = 16; off >= 1; off >>= 1) m = fmaxf(m, __shfl_xor(m, off, 64));
      if (s == 0) orow[j] = m;
    }
  }
}

// ---------------------------------------------------------------------------
extern "C" void kernel_launch(void* const* d_in, const int* in_sizes, int n_in,
                              void* d_out, int out_size, void* d_ws, size_t ws_size,
                              hipStream_t stream) {
  if (n_in < 20 || ws_size < WS_NEED) return;
  const float* xyz = (const float*)d_in[0];
  const float* feat = (const float*)d_in[1];
  const float* W0 = (const float*)d_in[2];
  const float* b0 = (const float*)d_in[3];
  const float* g0 = (const float*)d_in[4];
  const float* be0 = (const float*)d_in[5];
  const float* m0 = (const float*)d_in[6];
  const float* v0 = (const float*)d_in[7];
  const float* W1 = (const float*)d_in[8];
  const float* b1 = (const float*)d_in[9];
  const float* g1 = (const float*)d_in[10];
  const float* be1 = (const float*)d_in[11];
  const float* m1 = (const float*)d_in[12];
  const float* v1 = (const float*)d_in[13];
  const float* W2 = (const float*)d_in[14];
  const float* b2 = (const float*)d_in[15];
  const float* g2 = (const float*)d_in[16];
  const float* be2 = (const float*)d_in[17];
  const float* m2 = (const float*)d_in[18];
  const float* v2 = (const float*)d_in[19];

  char* ws = (char*)d_ws;
  float* featT = (float*)(ws + OFF_FEATT);
  float* nxyz = (float*)(ws + OFF_NEWXYZ);
  int* gidx = (int*)(ws + OFF_GIDX);
  float* wt0 = (float*)(ws + OFF_WT0);
  float* bp0 = (float*)(ws + OFF_BP0);
  float* wt1 = (float*)(ws + OFF_WT1);
  float* bp1 = (float*)(ws + OFF_BP1);
  float* wt2 = (float*)(ws + OFF_WT2);
  float* bp2 = (float*)(ws + OFF_BP2);

  float* out_xyz = (float*)d_out;                         // [16,1024,3]
  float* out_feat = (float*)d_out + NBATCH * NPOINT * 3;  // [16,1024,128]

  hipLaunchKernelGGL(prep_kernel, dim3(1), dim3(256), 0, stream,
                     W0, b0, g0, be0, m0, v0, W1, b1, g1, be1, m1, v1,
                     W2, b2, g2, be2, m2, v2, wt0, bp0, wt1, bp1, wt2, bp2);
  hipLaunchKernelGGL(transpose_kernel, dim3(NPTS / 32, NCH / 32, NBATCH), dim3(32, 8), 0, stream,
                     feat, featT);
  hipLaunchKernelGGL(fps_kernel, dim3(NBATCH), dim3(1024), 0, stream, xyz, nxyz, out_xyz);
  hipLaunchKernelGGL(topk_kernel, dim3(NBATCH * NPOINT), dim3(256), 0, stream, xyz, nxyz, gidx);
  hipLaunchKernelGGL(mlp_kernel, dim3(NBATCH * NPOINT / 2), dim3(256), 0, stream,
                     xyz, featT, nxyz, gidx, wt0, bp0, wt1, bp1, wt2, bp2, out_feat);
}

// Round 4
// 1443.509 us; speedup vs baseline: 1.4093x; 1.2325x over previous
//
#include <hip/hip_runtime.h>
#include <stdint.h>

#pragma clang fp contract(off)

typedef unsigned long long u64;
typedef float __attribute__((ext_vector_type(2))) f32x2;

#define NBATCH 16
#define NPTS   4096
#define NCH    64
#define NPOINT 1024
#define NSAMP  32

// ---- workspace byte offsets ----
#define OFF_FEATT   0u          // 16*4096*64*4 = 16777216
#define OFF_NEWXYZ  16777216u   // 16*1024*3*4 = 196608
#define OFF_GIDX    16973824u   // 16*1024*32*4 = 2097152
#define OFF_WT0     19070976u   // 67*64*4 = 17152
#define OFF_BP0     19088128u   // 64*4 (pad 256)
#define OFF_WT1     19088384u   // 64*64*4 = 16384
#define OFF_BP1     19104768u   // pad 256
#define OFF_WT2     19105024u   // 64*128*4 = 32768
#define OFF_BP2     19137792u   // pad 512
#define WS_NEED     19138304u

// Monotone map: float bits -> unsigned preserving total order (neg < pos).
__device__ __forceinline__ unsigned fkey(float f) {
  unsigned b = __float_as_uint(f);
  unsigned mask = ((unsigned)((int)b >> 31)) | 0x80000000u;
  return b ^ mask;
}

__device__ __forceinline__ f32x2 vmin2(f32x2 a, f32x2 b) {
  f32x2 r; r.x = fminf(a.x, b.x); r.y = fminf(a.y, b.y); return r;
}
__device__ __forceinline__ f32x2 vmax2(f32x2 a, f32x2 b) {
  f32x2 r; r.x = fmaxf(a.x, b.x); r.y = fmaxf(a.y, b.y); return r;
}

// ---------------------------------------------------------------------------
// Fold BN (eval) into conv weights/bias; transpose W to [c][o].
// ---------------------------------------------------------------------------
__global__ __launch_bounds__(256) void prep_kernel(
    const float* __restrict__ W0, const float* __restrict__ b0, const float* __restrict__ g0,
    const float* __restrict__ be0, const float* __restrict__ m0, const float* __restrict__ v0,
    const float* __restrict__ W1, const float* __restrict__ b1, const float* __restrict__ g1,
    const float* __restrict__ be1, const float* __restrict__ m1, const float* __restrict__ v1,
    const float* __restrict__ W2, const float* __restrict__ b2, const float* __restrict__ g2,
    const float* __restrict__ be2, const float* __restrict__ m2, const float* __restrict__ v2,
    float* __restrict__ wt0, float* __restrict__ bp0,
    float* __restrict__ wt1, float* __restrict__ bp1,
    float* __restrict__ wt2, float* __restrict__ bp2) {
  int t = threadIdx.x;
  for (int i = t; i < 64 * 67; i += 256) {
    int o = i / 67, c = i % 67;
    float s = g0[o] / sqrtf(v0[o] + 1e-5f);
    wt0[c * 64 + o] = W0[o * 67 + c] * s;
  }
  for (int o = t; o < 64; o += 256) {
    float s = g0[o] / sqrtf(v0[o] + 1e-5f);
    bp0[o] = (b0[o] - m0[o]) * s + be0[o];
  }
  for (int i = t; i < 64 * 64; i += 256) {
    int o = i / 64, c = i % 64;
    float s = g1[o] / sqrtf(v1[o] + 1e-5f);
    wt1[c * 64 + o] = W1[o * 64 + c] * s;
  }
  for (int o = t; o < 64; o += 256) {
    float s = g1[o] / sqrtf(v1[o] + 1e-5f);
    bp1[o] = (b1[o] - m1[o]) * s + be1[o];
  }
  for (int i = t; i < 128 * 64; i += 256) {
    int o = i / 64, c = i % 64;
    float s = g2[o] / sqrtf(v2[o] + 1e-5f);
    wt2[c * 128 + o] = W2[o * 64 + c] * s;
  }
  for (int o = t; o < 128; o += 256) {
    float s = g2[o] / sqrtf(v2[o] + 1e-5f);
    bp2[o] = (b2[o] - m2[o]) * s + be2[o];
  }
}

// ---------------------------------------------------------------------------
// features [B,C,N] -> featT [B,N,C]  (tiled 32x32 transpose)
// ---------------------------------------------------------------------------
__global__ __launch_bounds__(256) void transpose_kernel(const float* __restrict__ feat,
                                                        float* __restrict__ featT) {
  __shared__ float tile[32][33];
  int b = blockIdx.z;
  int n0 = blockIdx.x * 32;
  int c0 = blockIdx.y * 32;
  int tx = threadIdx.x, ty = threadIdx.y;  // 32 x 8
#pragma unroll
  for (int j = 0; j < 4; ++j)
    tile[ty + 8 * j][tx] = feat[b * (NCH * NPTS) + (c0 + ty + 8 * j) * NPTS + n0 + tx];
  __syncthreads();
#pragma unroll
  for (int j = 0; j < 4; ++j)
    featT[b * (NPTS * NCH) + (size_t)(n0 + ty + 8 * j) * NCH + c0 + tx] = tile[tx][ty + 8 * j];
}

// ---------------------------------------------------------------------------
// Exact farthest-point sampling. One block per batch, 256 threads (1 wave per
// SIMD -> no redundant-issue serialization), 16 pts/thread as 8x f32x2
// (packed VOP3P fp32). contract(off); per-element order (dx^2+dy^2)+dz^2.
// Wave argmax: fmax tree + lowest-idx eq-scan, u64 key (valbits<<32 | ~idx)
// reduced via DPP; block = 3 u64 selects over 4 wave keys (double-buffered).
// Tie semantics: max value, then min index == jnp.argmax first-occurrence.
// ---------------------------------------------------------------------------
#define DPP_MAXSTEP(CTRL)                                                              \
  do {                                                                                 \
    unsigned lo = (unsigned)key, hi = (unsigned)(key >> 32);                           \
    unsigned slo = (unsigned)__builtin_amdgcn_update_dpp((int)lo, (int)lo, CTRL, 0xF, 0xF, false); \
    unsigned shi = (unsigned)__builtin_amdgcn_update_dpp((int)hi, (int)hi, CTRL, 0xF, 0xF, false); \
    u64 s = ((u64)shi << 32) | slo;                                                    \
    if (s > key) key = s;                                                              \
  } while (0)

__global__ __launch_bounds__(256) void fps_kernel(const float* __restrict__ xyz,
                                                  float* __restrict__ nxyz,
                                                  float* __restrict__ out_xyz) {
  __shared__ float sx[NPTS], sy[NPTS], sz[NPTS];
  __shared__ int sidx[NPOINT];
  __shared__ u64 wkey[2][4];
  int b = blockIdx.x;
  int t = threadIdx.x;
  const float* X = xyz + (size_t)b * NPTS * 3;

  f32x2 qx[8], qy[8], qz[8], d[8];
#pragma unroll
  for (int i = 0; i < 8; ++i) {
    int p0 = t + 256 * (2 * i);
    int p1 = t + 256 * (2 * i + 1);
    float x0 = X[p0 * 3 + 0], y0 = X[p0 * 3 + 1], z0 = X[p0 * 3 + 2];
    float x1 = X[p1 * 3 + 0], y1 = X[p1 * 3 + 1], z1 = X[p1 * 3 + 2];
    qx[i].x = x0; qx[i].y = x1;
    qy[i].x = y0; qy[i].y = y1;
    qz[i].x = z0; qz[i].y = z1;
    sx[p0] = x0; sy[p0] = y0; sz[p0] = z0;
    sx[p1] = x1; sy[p1] = y1; sz[p1] = z1;
    d[i].x = 1e10f; d[i].y = 1e10f;
  }
  if (t == 0) sidx[0] = 0;
  __syncthreads();

  int last = 0;
  for (int k = 1; k < NPOINT; ++k) {
    float lxs = sx[last], lys = sy[last], lzs = sz[last];
    f32x2 lx; lx.x = lxs; lx.y = lxs;
    f32x2 ly; ly.x = lys; ly.y = lys;
    f32x2 lz; lz.x = lzs; lz.y = lzs;
#pragma unroll
    for (int i = 0; i < 8; ++i) {
      f32x2 dx = qx[i] - lx, dy = qy[i] - ly, dz = qz[i] - lz;
      f32x2 dist = (dx * dx + dy * dy) + dz * dz;  // contract(off): exact order
      d[i] = vmin2(d[i], dist);
    }
    // max value over 16 components (exact compares; no NaN/-0 possible)
    f32x2 m0 = vmax2(vmax2(d[0], d[1]), vmax2(d[2], d[3]));
    f32x2 m1 = vmax2(vmax2(d[4], d[5]), vmax2(d[6], d[7]));
    f32x2 m = vmax2(m0, m1);
    float mv = fmaxf(m.x, m.y);
    // lowest global index attaining mv (descending j -> last write = lowest)
    int mp = t;
#pragma unroll
    for (int i = 7; i >= 0; --i) {
      if (d[i].y == mv) mp = t + 256 * (2 * i + 1);
      if (d[i].x == mv) mp = t + 256 * (2 * i);
    }

    u64 key = ((u64)__float_as_uint(mv) << 32) | (unsigned)(~(unsigned)mp);
    // wave64 max-reduce at VALU speed; lane 63 ends with the wave max
    DPP_MAXSTEP(0xB1);   // quad_perm xor1
    DPP_MAXSTEP(0x4E);   // quad_perm xor2
    DPP_MAXSTEP(0x124);  // row_ror:4
    DPP_MAXSTEP(0x128);  // row_ror:8   -> 16-lane rows uniform
    DPP_MAXSTEP(0x142);  // row_bcast15
    DPP_MAXSTEP(0x143);  // row_bcast31 -> lanes 32..63 have wave max

    int kb = k & 1;
    if ((t & 63) == 63) wkey[kb][t >> 6] = key;
    __syncthreads();
    u64 w0 = wkey[kb][0], w1 = wkey[kb][1], w2 = wkey[kb][2], w3 = wkey[kb][3];
    w0 = w0 > w1 ? w0 : w1;
    w2 = w2 > w3 ? w2 : w3;
    w0 = w0 > w2 ? w0 : w2;
    last = (int)(~(unsigned)w0);
    if (t == 0) sidx[k] = last;
    // no second barrier: wkey double-buffered on k&1
  }
  __syncthreads();
  for (int p = t; p < NPOINT; p += 256) {
    int g = sidx[p];
    int o = (b * NPOINT + p) * 3;
    float x = sx[g], y = sy[g], z = sz[g];
    nxyz[o] = x; nxyz[o + 1] = y; nxyz[o + 2] = z;
    out_xyz[o] = x; out_xyz[o + 1] = y; out_xyz[o + 2] = z;
  }
}

// ---------------------------------------------------------------------------
// 32 nearest neighbors per sampled point. One block per (b,p), 256 thr x 16.
// ---------------------------------------------------------------------------
__global__ __launch_bounds__(256) void topk_kernel(const float* __restrict__ xyz,
                                                   const float* __restrict__ nxyz,
                                                   int* __restrict__ gidx) {
  __shared__ u64 tr[512];
  int blk = blockIdx.x;  // b*1024 + p
  int b = blk >> 10;
  int t = threadIdx.x;
  const float* X = xyz + (size_t)b * NPTS * 3;
  float px = nxyz[blk * 3 + 0], py = nxyz[blk * 3 + 1], pz = nxyz[blk * 3 + 2];
  float n2p = (px * px + py * py) + pz * pz;

  float dq[16];
#pragma unroll
  for (int i = 0; i < 16; ++i) {
    int n = t + 256 * i;
    float x = X[n * 3 + 0], y = X[n * 3 + 1], z = X[n * 3 + 2];
    float n2x = (x * x + y * y) + z * z;
    float dot = fmaf(pz, z, fmaf(py, y, px * x));
    dq[i] = (n2p + n2x) - 2.0f * dot;
  }
  float mv = dq[0];
  int mp = t;
#pragma unroll
  for (int i = 1; i < 16; ++i) {
    if (dq[i] < mv) { mv = dq[i]; mp = t + 256 * i; }
  }
  tr[256 + t] = ((u64)fkey(mv) << 32) | (unsigned)mp;
  __syncthreads();
  for (int lvl = 128; lvl >= 1; lvl >>= 1) {
    if (t < lvl) {
      u64 a = tr[2 * (lvl + t)], c = tr[2 * (lvl + t) + 1];
      tr[lvl + t] = a < c ? a : c;
    }
    __syncthreads();
  }
  int* go = gidx + (size_t)blk * NSAMP;
  for (int k = 0; k < NSAMP; ++k) {
    u64 root = tr[1];
    int wp = (int)(root & 0xffffffffull);
    if (t == 0) go[k] = wp;
    __syncthreads();  // everyone read root before owner mutates the tree
    if ((wp & 255) == t) {
      int slot = wp >> 8;
#pragma unroll
      for (int i = 0; i < 16; ++i)
        if (i == slot) dq[i] = __int_as_float(0x7f800000);
      float nv = dq[0];
      int np2 = t;
#pragma unroll
      for (int i = 1; i < 16; ++i) {
        if (dq[i] < nv) { nv = dq[i]; np2 = t + 256 * i; }
      }
      int nd = 256 + t;
      tr[nd] = ((u64)fkey(nv) << 32) | (unsigned)np2;
      nd >>= 1;
      while (nd >= 1) {
        u64 a = tr[2 * nd], c = tr[2 * nd + 1];
        tr[nd] = a < c ? a : c;
        nd >>= 1;
      }
    }
    __syncthreads();
  }
}

// ---------------------------------------------------------------------------
// Gather + 3-layer pointwise MLP (BN folded) + max over 32 samples.
// ---------------------------------------------------------------------------
__global__ __launch_bounds__(256) void mlp_kernel(
    const float* __restrict__ xyz, const float* __restrict__ featT,
    const float* __restrict__ nxyz, const int* __restrict__ gidx,
    const float* __restrict__ wt0, const float* __restrict__ bp0,
    const float* __restrict__ wt1, const float* __restrict__ bp1,
    const float* __restrict__ wt2, const float* __restrict__ bp2,
    float* __restrict__ outF) {
  __shared__ float XA[2][32][69];
  __shared__ float XB[2][32][69];
  int blk = blockIdx.x;
  int b = blk >> 9;
  int pb = (blk & 511) << 1;
  int t = threadIdx.x;

  for (int u = t; u < 2 * 32 * 67; u += 256) {
    int pt = u / (32 * 67);
    int r = u - pt * (32 * 67);
    int s = r / 67;
    int c = r - s * 67;
    int pp = pb + pt;
    int g = gidx[(size_t)(b * NPOINT + pp) * NSAMP + s];
    float val;
    if (c < 3)
      val = xyz[(size_t)(b * NPTS + g) * 3 + c] - nxyz[(size_t)(b * NPOINT + pp) * 3 + c];
    else
      val = featT[(size_t)(b * NPTS + g) * NCH + (c - 3)];
    XA[pt][s][c] = val;
  }
  __syncthreads();

  int w = __builtin_amdgcn_readfirstlane((int)(threadIdx.x >> 6));
  int l = t & 63;
  int s = l & 31;
  int pt = l >> 5;

  {  // L0: XA[*,*,0:67] -> XB[*,*,0:64]
    int ob = w * 16;
    float acc[16];
#pragma unroll
    for (int j = 0; j < 16; ++j) acc[j] = bp0[ob + j];
    for (int c = 0; c < 67; ++c) {
      float xv = XA[pt][s][c];
      const float* wr = wt0 + c * 64 + ob;
#pragma unroll
      for (int j = 0; j < 16; ++j) acc[j] = fmaf(xv, wr[j], acc[j]);
    }
#pragma unroll
    for (int j = 0; j < 16; ++j) XB[pt][s][ob + j] = fmaxf(acc[j], 0.0f);
  }
  __syncthreads();

  {  // L1: XB -> XA[*,*,0:64]
    int ob = w * 16;
    float acc[16];
#pragma unroll
    for (int j = 0; j < 16; ++j) acc[j] = bp1[ob + j];
    for (int c = 0; c < 64; ++c) {
      float xv = XB[pt][s][c];
      const float* wr = wt1 + c * 64 + ob;
#pragma unroll
      for (int j = 0; j < 16; ++j) acc[j] = fmaf(xv, wr[j], acc[j]);
    }
#pragma unroll
    for (int j = 0; j < 16; ++j) XA[pt][s][ob + j] = fmaxf(acc[j], 0.0f);
  }
  __syncthreads();

  {  // L2: XA -> regs; ReLU; butterfly max over the 32 s-lanes; write out
    int ob = w * 32;
    float acc[32];
#pragma unroll
    for (int j = 0; j < 32; ++j) acc[j] = bp2[ob + j];
    for (int c = 0; c < 64; ++c) {
      float xv = XA[pt][s][c];
      const float* wr = wt2 + c * 128 + ob;
#pragma unroll
      for (int j = 0; j < 32; ++j) acc[j] = fmaf(xv, wr[j], acc[j]);
    }
    float* orow = outF + (size_t)(b * NPOINT + pb + pt) * 128 + ob;
#pragma unroll
    for (int j = 0; j < 32; ++j) {
      float m = fmaxf(acc[j], 0.0f);
#pragma unroll
      for (int off = 16; off >= 1; off >>= 1) m = fmaxf(m, __shfl_xor(m, off, 64));
      if (s == 0) orow[j] = m;
    }
  }
}

// ---------------------------------------------------------------------------
extern "C" void kernel_launch(void* const* d_in, const int* in_sizes, int n_in,
                              void* d_out, int out_size, void* d_ws, size_t ws_size,
                              hipStream_t stream) {
  if (n_in < 20 || ws_size < WS_NEED) return;
  const float* xyz = (const float*)d_in[0];
  const float* feat = (const float*)d_in[1];
  const float* W0 = (const float*)d_in[2];
  const float* b0 = (const float*)d_in[3];
  const float* g0 = (const float*)d_in[4];
  const float* be0 = (const float*)d_in[5];
  const float* m0 = (const float*)d_in[6];
  const float* v0 = (const float*)d_in[7];
  const float* W1 = (const float*)d_in[8];
  const float* b1 = (const float*)d_in[9];
  const float* g1 = (const float*)d_in[10];
  const float* be1 = (const float*)d_in[11];
  const float* m1 = (const float*)d_in[12];
  const float* v1 = (const float*)d_in[13];
  const float* W2 = (const float*)d_in[14];
  const float* b2 = (const float*)d_in[15];
  const float* g2 = (const float*)d_in[16];
  const float* be2 = (const float*)d_in[17];
  const float* m2 = (const float*)d_in[18];
  const float* v2 = (const float*)d_in[19];

  char* ws = (char*)d_ws;
  float* featT = (float*)(ws + OFF_FEATT);
  float* nxyz = (float*)(ws + OFF_NEWXYZ);
  int* gidx = (int*)(ws + OFF_GIDX);
  float* wt0 = (float*)(ws + OFF_WT0);
  float* bp0 = (float*)(ws + OFF_BP0);
  float* wt1 = (float*)(ws + OFF_WT1);
  float* bp1 = (float*)(ws + OFF_BP1);
  float* wt2 = (float*)(ws + OFF_WT2);
  float* bp2 = (float*)(ws + OFF_BP2);

  float* out_xyz = (float*)d_out;                         // [16,1024,3]
  float* out_feat = (float*)d_out + NBATCH * NPOINT * 3;  // [16,1024,128]

  hipLaunchKernelGGL(prep_kernel, dim3(1), dim3(256), 0, stream,
                     W0, b0, g0, be0, m0, v0, W1, b1, g1, be1, m1, v1,
                     W2, b2, g2, be2, m2, v2, wt0, bp0, wt1, bp1, wt2, bp2);
  hipLaunchKernelGGL(transpose_kernel, dim3(NPTS / 32, NCH / 32, NBATCH), dim3(32, 8), 0, stream,
                     feat, featT);
  hipLaunchKernelGGL(fps_kernel, dim3(NBATCH), dim3(256), 0, stream, xyz, nxyz, out_xyz);
  hipLaunchKernelGGL(topk_kernel, dim3(NBATCH * NPOINT), dim3(256), 0, stream, xyz, nxyz, gidx);
  hipLaunchKernelGGL(mlp_kernel, dim3(NBATCH * NPOINT / 2), dim3(256), 0, stream,
                     xyz, featT, nxyz, gidx, wt0, bp0, wt1, bp1, wt2, bp2, out_feat);
}

// Round 6
// 1401.299 us; speedup vs baseline: 1.4517x; 1.0301x over previous
//
#include <hip/hip_runtime.h>
#include <stdint.h>

#pragma clang fp contract(off)

typedef unsigned long long u64;

#define NBATCH 16
#define NPTS   4096
#define NCH    64
#define NPOINT 1024
#define NSAMP  32

// ---- workspace byte offsets ----
#define OFF_FEATT   0u          // 16*4096*64*4 = 16777216
#define OFF_NEWXYZ  16777216u   // 16*1024*3*4 = 196608
#define OFF_GIDX    16973824u   // 16*1024*32*4 = 2097152
#define OFF_WT0     19070976u   // 67*64*4 = 17152
#define OFF_BP0     19088128u   // 64*4 (pad 256)
#define OFF_WT1     19088384u   // 64*64*4 = 16384
#define OFF_BP1     19104768u   // pad 256
#define OFF_WT2     19105024u   // 64*128*4 = 32768
#define OFF_BP2     19137792u   // pad 512
#define WS_NEED     19138304u

// Monotone map: float bits -> unsigned preserving total order (neg < pos).
__device__ __forceinline__ unsigned fkey(float f) {
  unsigned b = __float_as_uint(f);
  unsigned mask = ((unsigned)((int)b >> 31)) | 0x80000000u;
  return b ^ mask;
}

__device__ __forceinline__ double mkkey(float v, unsigned lo) {
  // key = (bits(v) << 32) | lo, viewed as double. v in [0, 1e10] -> positive
  // double, never NaN/Inf -> u64 order == f64 order -> fmax == u64 max.
  return __longlong_as_double((long long)(((u64)__float_as_uint(v) << 32) | lo));
}

// ---------------------------------------------------------------------------
// Fold BN (eval) into conv weights/bias; transpose W to [c][o].
// ---------------------------------------------------------------------------
__global__ __launch_bounds__(256) void prep_kernel(
    const float* __restrict__ W0, const float* __restrict__ b0, const float* __restrict__ g0,
    const float* __restrict__ be0, const float* __restrict__ m0, const float* __restrict__ v0,
    const float* __restrict__ W1, const float* __restrict__ b1, const float* __restrict__ g1,
    const float* __restrict__ be1, const float* __restrict__ m1, const float* __restrict__ v1,
    const float* __restrict__ W2, const float* __restrict__ b2, const float* __restrict__ g2,
    const float* __restrict__ be2, const float* __restrict__ m2, const float* __restrict__ v2,
    float* __restrict__ wt0, float* __restrict__ bp0,
    float* __restrict__ wt1, float* __restrict__ bp1,
    float* __restrict__ wt2, float* __restrict__ bp2) {
  int t = threadIdx.x;
  for (int i = t; i < 64 * 67; i += 256) {
    int o = i / 67, c = i % 67;
    float s = g0[o] / sqrtf(v0[o] + 1e-5f);
    wt0[c * 64 + o] = W0[o * 67 + c] * s;
  }
  for (int o = t; o < 64; o += 256) {
    float s = g0[o] / sqrtf(v0[o] + 1e-5f);
    bp0[o] = (b0[o] - m0[o]) * s + be0[o];
  }
  for (int i = t; i < 64 * 64; i += 256) {
    int o = i / 64, c = i % 64;
    float s = g1[o] / sqrtf(v1[o] + 1e-5f);
    wt1[c * 64 + o] = W1[o * 64 + c] * s;
  }
  for (int o = t; o < 64; o += 256) {
    float s = g1[o] / sqrtf(v1[o] + 1e-5f);
    bp1[o] = (b1[o] - m1[o]) * s + be1[o];
  }
  for (int i = t; i < 128 * 64; i += 256) {
    int o = i / 64, c = i % 64;
    float s = g2[o] / sqrtf(v2[o] + 1e-5f);
    wt2[c * 128 + o] = W2[o * 64 + c] * s;
  }
  for (int o = t; o < 128; o += 256) {
    float s = g2[o] / sqrtf(v2[o] + 1e-5f);
    bp2[o] = (b2[o] - m2[o]) * s + be2[o];
  }
}

// ---------------------------------------------------------------------------
// features [B,C,N] -> featT [B,N,C]  (tiled 32x32 transpose)
// ---------------------------------------------------------------------------
__global__ __launch_bounds__(256) void transpose_kernel(const float* __restrict__ feat,
                                                        float* __restrict__ featT) {
  __shared__ float tile[32][33];
  int b = blockIdx.z;
  int n0 = blockIdx.x * 32;
  int c0 = blockIdx.y * 32;
  int tx = threadIdx.x, ty = threadIdx.y;  // 32 x 8
#pragma unroll
  for (int j = 0; j < 4; ++j)
    tile[ty + 8 * j][tx] = feat[b * (NCH * NPTS) + (c0 + ty + 8 * j) * NPTS + n0 + tx];
  __syncthreads();
#pragma unroll
  for (int j = 0; j < 4; ++j)
    featT[b * (NPTS * NCH) + (size_t)(n0 + ty + 8 * j) * NCH + c0 + tx] = tile[tx][ty + 8 * j];
}

// ---------------------------------------------------------------------------
// Exact farthest-point sampling. One block per batch, 256 threads x 16 pts.
// f64-key argmax: key = (bits(d)<<32)|~idx as positive double; fmax == u64
// max == (max value, then min index) — jnp.argmax first-occurrence exactly.
//  - per-thread: 15 v_max_f64 tree over 16 keys (lo words loop-invariant)
//  - wave: 6 DPP steps, each 2x v_mov_dpp + 1x v_max_f64 (no vcc hazards)
//  - block: lane63-of-wave -> LDS (double-buffered), 3 v_max_f64, 1 barrier
// Winner coords broadcast-read from LDS; t0 streams them to global.
// ---------------------------------------------------------------------------
#define DPP_MAXSTEP(CTRL)                                                                          \
  do {                                                                                             \
    u64 kb_ = (u64)__double_as_longlong(key);                                                      \
    unsigned lo_ = (unsigned)kb_, hi_ = (unsigned)(kb_ >> 32);                                     \
    unsigned slo = (unsigned)__builtin_amdgcn_update_dpp((int)lo_, (int)lo_, CTRL, 0xF, 0xF, false); \
    unsigned shi = (unsigned)__builtin_amdgcn_update_dpp((int)hi_, (int)hi_, CTRL, 0xF, 0xF, false); \
    key = fmax(key, __longlong_as_double((long long)(((u64)shi << 32) | slo)));                    \
  } while (0)

__global__ __launch_bounds__(256) void fps_kernel(const float* __restrict__ xyz,
                                                  float* __restrict__ nxyz,
                                                  float* __restrict__ out_xyz) {
  __shared__ float sx[NPTS], sy[NPTS], sz[NPTS];
  __shared__ double wkd[2][4];
  int b = blockIdx.x;
  int t = threadIdx.x;
  const float* X = xyz + (size_t)b * NPTS * 3;

  float qx[16], qy[16], qz[16], d[16];
  unsigned nio[16];  // ~global_idx, loop-invariant key low words
#pragma unroll
  for (int i = 0; i < 16; ++i) {
    int p = t + 256 * i;
    float x = X[p * 3 + 0], y = X[p * 3 + 1], z = X[p * 3 + 2];
    qx[i] = x; qy[i] = y; qz[i] = z;
    sx[p] = x; sy[p] = y; sz[p] = z;
    d[i] = 1e10f;
    nio[i] = ~(unsigned)p;
  }
  __syncthreads();

  float lx = sx[0], ly = sy[0], lz = sz[0];
  if (t == 0) {
    nxyz[(b * NPOINT) * 3 + 0] = lx; nxyz[(b * NPOINT) * 3 + 1] = ly; nxyz[(b * NPOINT) * 3 + 2] = lz;
    out_xyz[(b * NPOINT) * 3 + 0] = lx; out_xyz[(b * NPOINT) * 3 + 1] = ly; out_xyz[(b * NPOINT) * 3 + 2] = lz;
  }

  for (int k = 1; k < NPOINT; ++k) {
    // distance update: contract(off), exact order (dx^2+dy^2)+dz^2
#pragma unroll
    for (int i = 0; i < 16; ++i) {
      float dx = qx[i] - lx, dy = qy[i] - ly, dz = qz[i] - lz;
      float dist = (dx * dx + dy * dy) + dz * dz;
      d[i] = fminf(d[i], dist);
    }
    // 16 keys -> 15 v_max_f64 tree
    double k0 = fmax(mkkey(d[0], nio[0]), mkkey(d[1], nio[1]));
    double k1 = fmax(mkkey(d[2], nio[2]), mkkey(d[3], nio[3]));
    double k2 = fmax(mkkey(d[4], nio[4]), mkkey(d[5], nio[5]));
    double k3 = fmax(mkkey(d[6], nio[6]), mkkey(d[7], nio[7]));
    double k4 = fmax(mkkey(d[8], nio[8]), mkkey(d[9], nio[9]));
    double k5 = fmax(mkkey(d[10], nio[10]), mkkey(d[11], nio[11]));
    double k6 = fmax(mkkey(d[12], nio[12]), mkkey(d[13], nio[13]));
    double k7 = fmax(mkkey(d[14], nio[14]), mkkey(d[15], nio[15]));
    k0 = fmax(k0, k1); k2 = fmax(k2, k3); k4 = fmax(k4, k5); k6 = fmax(k6, k7);
    k0 = fmax(k0, k2); k4 = fmax(k4, k6);
    double key = fmax(k0, k4);

    // wave64 max-reduce; lane 63 ends with the wave max
    DPP_MAXSTEP(0xB1);   // quad_perm xor1
    DPP_MAXSTEP(0x4E);   // quad_perm xor2
    DPP_MAXSTEP(0x124);  // row_ror:4
    DPP_MAXSTEP(0x128);  // row_ror:8
    DPP_MAXSTEP(0x142);  // row_bcast15
    DPP_MAXSTEP(0x143);  // row_bcast31

    int kb = k & 1;
    if ((t & 63) == 63) wkd[kb][t >> 6] = key;
    __syncthreads();
    double w0 = wkd[kb][0], w1 = wkd[kb][1], w2 = wkd[kb][2], w3 = wkd[kb][3];
    w0 = fmax(w0, w1); w2 = fmax(w2, w3);
    w0 = fmax(w0, w2);
    int last = (int)(~(unsigned)(u64)__double_as_longlong(w0));
    lx = sx[last]; ly = sy[last]; lz = sz[last];  // broadcast LDS reads
    if (t == 0) {
      int o = (b * NPOINT + k) * 3;
      nxyz[o] = lx; nxyz[o + 1] = ly; nxyz[o + 2] = lz;
      out_xyz[o] = lx; out_xyz[o + 1] = ly; out_xyz[o + 2] = lz;
    }
    // no second barrier: wkd double-buffered on k&1
  }
}

// ---------------------------------------------------------------------------
// 32 nearest neighbors per sampled point. One block per (b,p), 256 thr x 16.
// ---------------------------------------------------------------------------
__global__ __launch_bounds__(256) void topk_kernel(const float* __restrict__ xyz,
                                                   const float* __restrict__ nxyz,
                                                   int* __restrict__ gidx) {
  __shared__ u64 tr[512];
  int blk = blockIdx.x;  // b*1024 + p
  int b = blk >> 10;
  int t = threadIdx.x;
  const float* X = xyz + (size_t)b * NPTS * 3;
  float px = nxyz[blk * 3 + 0], py = nxyz[blk * 3 + 1], pz = nxyz[blk * 3 + 2];
  float n2p = (px * px + py * py) + pz * pz;

  float dq[16];
#pragma unroll
  for (int i = 0; i < 16; ++i) {
    int n = t + 256 * i;
    float x = X[n * 3 + 0], y = X[n * 3 + 1], z = X[n * 3 + 2];
    float n2x = (x * x + y * y) + z * z;
    float dot = fmaf(pz, z, fmaf(py, y, px * x));
    dq[i] = (n2p + n2x) - 2.0f * dot;
  }
  float mv = dq[0];
  int mp = t;
#pragma unroll
  for (int i = 1; i < 16; ++i) {
    if (dq[i] < mv) { mv = dq[i]; mp = t + 256 * i; }
  }
  tr[256 + t] = ((u64)fkey(mv) << 32) | (unsigned)mp;
  __syncthreads();
  for (int lvl = 128; lvl >= 1; lvl >>= 1) {
    if (t < lvl) {
      u64 a = tr[2 * (lvl + t)], c = tr[2 * (lvl + t) + 1];
      tr[lvl + t] = a < c ? a : c;
    }
    __syncthreads();
  }
  int* go = gidx + (size_t)blk * NSAMP;
  for (int k = 0; k < NSAMP; ++k) {
    u64 root = tr[1];
    int wp = (int)(root & 0xffffffffull);
    if (t == 0) go[k] = wp;
    __syncthreads();  // everyone read root before owner mutates the tree
    if ((wp & 255) == t) {
      int slot = wp >> 8;
#pragma unroll
      for (int i = 0; i < 16; ++i)
        if (i == slot) dq[i] = __int_as_float(0x7f800000);
      float nv = dq[0];
      int np2 = t;
#pragma unroll
      for (int i = 1; i < 16; ++i) {
        if (dq[i] < nv) { nv = dq[i]; np2 = t + 256 * i; }
      }
      int nd = 256 + t;
      tr[nd] = ((u64)fkey(nv) << 32) | (unsigned)np2;
      nd >>= 1;
      while (nd >= 1) {
        u64 a = tr[2 * nd], c = tr[2 * nd + 1];
        tr[nd] = a < c ? a : c;
        nd >>= 1;
      }
    }
    __syncthreads();
  }
}

// ---------------------------------------------------------------------------
// Gather + 3-layer pointwise MLP (BN folded) + max over 32 samples.
// ---------------------------------------------------------------------------
__global__ __launch_bounds__(256) void mlp_kernel(
    const float* __restrict__ xyz, const float* __restrict__ featT,
    const float* __restrict__ nxyz, const int* __restrict__ gidx,
    const float* __restrict__ wt0, const float* __restrict__ bp0,
    const float* __restrict__ wt1, const float* __restrict__ bp1,
    const float* __restrict__ wt2, const float* __restrict__ bp2,
    float* __restrict__ outF) {
  __shared__ float XA[2][32][69];
  __shared__ float XB[2][32][69];
  int blk = blockIdx.x;
  int b = blk >> 9;
  int pb = (blk & 511) << 1;
  int t = threadIdx.x;

  for (int u = t; u < 2 * 32 * 67; u += 256) {
    int pt = u / (32 * 67);
    int r = u - pt * (32 * 67);
    int s = r / 67;
    int c = r - s * 67;
    int pp = pb + pt;
    int g = gidx[(size_t)(b * NPOINT + pp) * NSAMP + s];
    float val;
    if (c < 3)
      val = xyz[(size_t)(b * NPTS + g) * 3 + c] - nxyz[(size_t)(b * NPOINT + pp) * 3 + c];
    else
      val = featT[(size_t)(b * NPTS + g) * NCH + (c - 3)];
    XA[pt][s][c] = val;
  }
  __syncthreads();

  int w = __builtin_amdgcn_readfirstlane((int)(threadIdx.x >> 6));
  int l = t & 63;
  int s = l & 31;
  int pt = l >> 5;

  {  // L0: XA[*,*,0:67] -> XB[*,*,0:64]
    int ob = w * 16;
    float acc[16];
#pragma unroll
    for (int j = 0; j < 16; ++j) acc[j] = bp0[ob + j];
    for (int c = 0; c < 67; ++c) {
      float xv = XA[pt][s][c];
      const float* wr = wt0 + c * 64 + ob;
#pragma unroll
      for (int j = 0; j < 16; ++j) acc[j] = fmaf(xv, wr[j], acc[j]);
    }
#pragma unroll
    for (int j = 0; j < 16; ++j) XB[pt][s][ob + j] = fmaxf(acc[j], 0.0f);
  }
  __syncthreads();

  {  // L1: XB -> XA[*,*,0:64]
    int ob = w * 16;
    float acc[16];
#pragma unroll
    for (int j = 0; j < 16; ++j) acc[j] = bp1[ob + j];
    for (int c = 0; c < 64; ++c) {
      float xv = XB[pt][s][c];
      const float* wr = wt1 + c * 64 + ob;
#pragma unroll
      for (int j = 0; j < 16; ++j) acc[j] = fmaf(xv, wr[j], acc[j]);
    }
#pragma unroll
    for (int j = 0; j < 16; ++j) XA[pt][s][ob + j] = fmaxf(acc[j], 0.0f);
  }
  __syncthreads();

  {  // L2: XA -> regs; ReLU; butterfly max over the 32 s-lanes; write out
    int ob = w * 32;
    float acc[32];
#pragma unroll
    for (int j = 0; j < 32; ++j) acc[j] = bp2[ob + j];
    for (int c = 0; c < 64; ++c) {
      float xv = XA[pt][s][c];
      const float* wr = wt2 + c * 128 + ob;
#pragma unroll
      for (int j = 0; j < 32; ++j) acc[j] = fmaf(xv, wr[j], acc[j]);
    }
    float* orow = outF + (size_t)(b * NPOINT + pb + pt) * 128 + ob;
#pragma unroll
    for (int j = 0; j < 32; ++j) {
      float m = fmaxf(acc[j], 0.0f);
#pragma unroll
      for (int off = 16; off >= 1; off >>= 1) m = fmaxf(m, __shfl_xor(m, off, 64));
      if (s == 0) orow[j] = m;
    }
  }
}

// ---------------------------------------------------------------------------
extern "C" void kernel_launch(void* const* d_in, const int* in_sizes, int n_in,
                              void* d_out, int out_size, void* d_ws, size_t ws_size,
                              hipStream_t stream) {
  if (n_in < 20 || ws_size < WS_NEED) return;
  const float* xyz = (const float*)d_in[0];
  const float* feat = (const float*)d_in[1];
  const float* W0 = (const float*)d_in[2];
  const float* b0 = (const float*)d_in[3];
  const float* g0 = (const float*)d_in[4];
  const float* be0 = (const float*)d_in[5];
  const float* m0 = (const float*)d_in[6];
  const float* v0 = (const float*)d_in[7];
  const float* W1 = (const float*)d_in[8];
  const float* b1 = (const float*)d_in[9];
  const float* g1 = (const float*)d_in[10];
  const float* be1 = (const float*)d_in[11];
  const float* m1 = (const float*)d_in[12];
  const float* v1 = (const float*)d_in[13];
  const float* W2 = (const float*)d_in[14];
  const float* b2 = (const float*)d_in[15];
  const float* g2 = (const float*)d_in[16];
  const float* be2 = (const float*)d_in[17];
  const float* m2 = (const float*)d_in[18];
  const float* v2 = (const float*)d_in[19];

  char* ws = (char*)d_ws;
  float* featT = (float*)(ws + OFF_FEATT);
  float* nxyz = (float*)(ws + OFF_NEWXYZ);
  int* gidx = (int*)(ws + OFF_GIDX);
  float* wt0 = (float*)(ws + OFF_WT0);
  float* bp0 = (float*)(ws + OFF_BP0);
  float* wt1 = (float*)(ws + OFF_WT1);
  float* bp1 = (float*)(ws + OFF_BP1);
  float* wt2 = (float*)(ws + OFF_WT2);
  float* bp2 = (float*)(ws + OFF_BP2);

  float* out_xyz = (float*)d_out;                         // [16,1024,3]
  float* out_feat = (float*)d_out + NBATCH * NPOINT * 3;  // [16,1024,128]

  hipLaunchKernelGGL(prep_kernel, dim3(1), dim3(256), 0, stream,
                     W0, b0, g0, be0, m0, v0, W1, b1, g1, be1, m1, v1,
                     W2, b2, g2, be2, m2, v2, wt0, bp0, wt1, bp1, wt2, bp2);
  hipLaunchKernelGGL(transpose_kernel, dim3(NPTS / 32, NCH / 32, NBATCH), dim3(32, 8), 0, stream,
                     feat, featT);
  hipLaunchKernelGGL(fps_kernel, dim3(NBATCH), dim3(256), 0, stream, xyz, nxyz, out_xyz);
  hipLaunchKernelGGL(topk_kernel, dim3(NBATCH * NPOINT), dim3(256), 0, stream, xyz, nxyz, gidx);
  hipLaunchKernelGGL(mlp_kernel, dim3(NBATCH * NPOINT / 2), dim3(256), 0, stream,
                     xyz, featT, nxyz, gidx, wt0, bp0, wt1, bp1, wt2, bp2, out_feat);
}

// Round 8
// 1190.798 us; speedup vs baseline: 1.7084x; 1.1768x over previous
//
#include <hip/hip_runtime.h>
#include <stdint.h>

#pragma clang fp contract(off)

typedef unsigned long long u64;

#define NBATCH 16
#define NPTS   4096
#define NCH    64
#define NPOINT 1024
#define NSAMP  32

// ---- workspace byte offsets ----
#define OFF_FEATT   0u          // 16*4096*64*4 = 16777216
#define OFF_NEWXYZ  16777216u   // 16*1024*3*4 = 196608
#define OFF_GIDX    16973824u   // 16*1024*32*4 = 2097152
#define OFF_WT0     19070976u   // 67*64*4 = 17152
#define OFF_BP0     19088128u   // 64*4 (pad 256)
#define OFF_WT1     19088384u   // 64*64*4 = 16384
#define OFF_BP1     19104768u   // pad 256
#define OFF_WT2     19105024u   // 64*128*4 = 32768
#define OFF_BP2     19137792u   // pad 512
#define WS_NEED     19138304u

// Monotone map: float bits -> unsigned preserving total order (neg < pos).
__device__ __forceinline__ unsigned fkey(float f) {
  unsigned b = __float_as_uint(f);
  unsigned mask = ((unsigned)((int)b >> 31)) | 0x80000000u;
  return b ^ mask;
}

__device__ __forceinline__ double mkkey(float v, unsigned lo) {
  // key = (bits(v) << 32) | lo, viewed as double. v in [0, 1e10] -> positive
  // double, never NaN/Inf -> u64 order == f64 order -> fmax == u64 max.
  return __longlong_as_double((long long)(((u64)__float_as_uint(v) << 32) | lo));
}

__device__ __forceinline__ int mbcnt64(u64 m) {
  int c = __builtin_amdgcn_mbcnt_lo((unsigned)m, 0);
  return __builtin_amdgcn_mbcnt_hi((unsigned)(m >> 32), c);
}

// ---------------------------------------------------------------------------
// Fold BN (eval) into conv weights/bias; transpose W to [c][o].
// ---------------------------------------------------------------------------
__global__ __launch_bounds__(256) void prep_kernel(
    const float* __restrict__ W0, const float* __restrict__ b0, const float* __restrict__ g0,
    const float* __restrict__ be0, const float* __restrict__ m0, const float* __restrict__ v0,
    const float* __restrict__ W1, const float* __restrict__ b1, const float* __restrict__ g1,
    const float* __restrict__ be1, const float* __restrict__ m1, const float* __restrict__ v1,
    const float* __restrict__ W2, const float* __restrict__ b2, const float* __restrict__ g2,
    const float* __restrict__ be2, const float* __restrict__ m2, const float* __restrict__ v2,
    float* __restrict__ wt0, float* __restrict__ bp0,
    float* __restrict__ wt1, float* __restrict__ bp1,
    float* __restrict__ wt2, float* __restrict__ bp2) {
  int t = threadIdx.x;
  for (int i = t; i < 64 * 67; i += 256) {
    int o = i / 67, c = i % 67;
    float s = g0[o] / sqrtf(v0[o] + 1e-5f);
    wt0[c * 64 + o] = W0[o * 67 + c] * s;
  }
  for (int o = t; o < 64; o += 256) {
    float s = g0[o] / sqrtf(v0[o] + 1e-5f);
    bp0[o] = (b0[o] - m0[o]) * s + be0[o];
  }
  for (int i = t; i < 64 * 64; i += 256) {
    int o = i / 64, c = i % 64;
    float s = g1[o] / sqrtf(v1[o] + 1e-5f);
    wt1[c * 64 + o] = W1[o * 64 + c] * s;
  }
  for (int o = t; o < 64; o += 256) {
    float s = g1[o] / sqrtf(v1[o] + 1e-5f);
    bp1[o] = (b1[o] - m1[o]) * s + be1[o];
  }
  for (int i = t; i < 128 * 64; i += 256) {
    int o = i / 64, c = i % 64;
    float s = g2[o] / sqrtf(v2[o] + 1e-5f);
    wt2[c * 128 + o] = W2[o * 64 + c] * s;
  }
  for (int o = t; o < 128; o += 256) {
    float s = g2[o] / sqrtf(v2[o] + 1e-5f);
    bp2[o] = (b2[o] - m2[o]) * s + be2[o];
  }
}

// ---------------------------------------------------------------------------
// features [B,C,N] -> featT [B,N,C]  (tiled 32x32 transpose)
// ---------------------------------------------------------------------------
__global__ __launch_bounds__(256) void transpose_kernel(const float* __restrict__ feat,
                                                        float* __restrict__ featT) {
  __shared__ float tile[32][33];
  int b = blockIdx.z;
  int n0 = blockIdx.x * 32;
  int c0 = blockIdx.y * 32;
  int tx = threadIdx.x, ty = threadIdx.y;  // 32 x 8
#pragma unroll
  for (int j = 0; j < 4; ++j)
    tile[ty + 8 * j][tx] = feat[b * (NCH * NPTS) + (c0 + ty + 8 * j) * NPTS + n0 + tx];
  __syncthreads();
#pragma unroll
  for (int j = 0; j < 4; ++j)
    featT[b * (NPTS * NCH) + (size_t)(n0 + ty + 8 * j) * NCH + c0 + tx] = tile[tx][ty + 8 * j];
}

// ---------------------------------------------------------------------------
// Exact farthest-point sampling. One block per batch, 256 threads x 16 pts.
// f64-key argmax (see R4 notes). Unchanged from R6 (measured 582 us).
// ---------------------------------------------------------------------------
#define DPP_MAXSTEP(CTRL)                                                                          \
  do {                                                                                             \
    u64 kb_ = (u64)__double_as_longlong(key);                                                      \
    unsigned lo_ = (unsigned)kb_, hi_ = (unsigned)(kb_ >> 32);                                     \
    unsigned slo = (unsigned)__builtin_amdgcn_update_dpp((int)lo_, (int)lo_, CTRL, 0xF, 0xF, false); \
    unsigned shi = (unsigned)__builtin_amdgcn_update_dpp((int)hi_, (int)hi_, CTRL, 0xF, 0xF, false); \
    key = fmax(key, __longlong_as_double((long long)(((u64)shi << 32) | slo)));                    \
  } while (0)

__global__ __launch_bounds__(256) void fps_kernel(const float* __restrict__ xyz,
                                                  float* __restrict__ nxyz,
                                                  float* __restrict__ out_xyz) {
  __shared__ float sx[NPTS], sy[NPTS], sz[NPTS];
  __shared__ double wkd[2][4];
  int b = blockIdx.x;
  int t = threadIdx.x;
  const float* X = xyz + (size_t)b * NPTS * 3;

  float qx[16], qy[16], qz[16], d[16];
  unsigned nio[16];  // ~global_idx, loop-invariant key low words
#pragma unroll
  for (int i = 0; i < 16; ++i) {
    int p = t + 256 * i;
    float x = X[p * 3 + 0], y = X[p * 3 + 1], z = X[p * 3 + 2];
    qx[i] = x; qy[i] = y; qz[i] = z;
    sx[p] = x; sy[p] = y; sz[p] = z;
    d[i] = 1e10f;
    nio[i] = ~(unsigned)p;
  }
  __syncthreads();

  float lx = sx[0], ly = sy[0], lz = sz[0];
  if (t == 0) {
    nxyz[(b * NPOINT) * 3 + 0] = lx; nxyz[(b * NPOINT) * 3 + 1] = ly; nxyz[(b * NPOINT) * 3 + 2] = lz;
    out_xyz[(b * NPOINT) * 3 + 0] = lx; out_xyz[(b * NPOINT) * 3 + 1] = ly; out_xyz[(b * NPOINT) * 3 + 2] = lz;
  }

  for (int k = 1; k < NPOINT; ++k) {
    // distance update: contract(off), exact order (dx^2+dy^2)+dz^2
#pragma unroll
    for (int i = 0; i < 16; ++i) {
      float dx = qx[i] - lx, dy = qy[i] - ly, dz = qz[i] - lz;
      float dist = (dx * dx + dy * dy) + dz * dz;
      d[i] = fminf(d[i], dist);
    }
    // 16 keys -> 15 v_max_f64 tree
    double k0 = fmax(mkkey(d[0], nio[0]), mkkey(d[1], nio[1]));
    double k1 = fmax(mkkey(d[2], nio[2]), mkkey(d[3], nio[3]));
    double k2 = fmax(mkkey(d[4], nio[4]), mkkey(d[5], nio[5]));
    double k3 = fmax(mkkey(d[6], nio[6]), mkkey(d[7], nio[7]));
    double k4 = fmax(mkkey(d[8], nio[8]), mkkey(d[9], nio[9]));
    double k5 = fmax(mkkey(d[10], nio[10]), mkkey(d[11], nio[11]));
    double k6 = fmax(mkkey(d[12], nio[12]), mkkey(d[13], nio[13]));
    double k7 = fmax(mkkey(d[14], nio[14]), mkkey(d[15], nio[15]));
    k0 = fmax(k0, k1); k2 = fmax(k2, k3); k4 = fmax(k4, k5); k6 = fmax(k6, k7);
    k0 = fmax(k0, k2); k4 = fmax(k4, k6);
    double key = fmax(k0, k4);

    // wave64 max-reduce; lane 63 ends with the wave max
    DPP_MAXSTEP(0xB1);   // quad_perm xor1
    DPP_MAXSTEP(0x4E);   // quad_perm xor2
    DPP_MAXSTEP(0x124);  // row_ror:4
    DPP_MAXSTEP(0x128);  // row_ror:8
    DPP_MAXSTEP(0x142);  // row_bcast15
    DPP_MAXSTEP(0x143);  // row_bcast31

    int kb = k & 1;
    if ((t & 63) == 63) wkd[kb][t >> 6] = key;
    __syncthreads();
    double w0 = wkd[kb][0], w1 = wkd[kb][1], w2 = wkd[kb][2], w3 = wkd[kb][3];
    w0 = fmax(w0, w1); w2 = fmax(w2, w3);
    w0 = fmax(w0, w2);
    int last = (int)(~(unsigned)(u64)__double_as_longlong(w0));
    lx = sx[last]; ly = sy[last]; lz = sz[last];  // broadcast LDS reads
    if (t == 0) {
      int o = (b * NPOINT + k) * 3;
      nxyz[o] = lx; nxyz[o + 1] = ly; nxyz[o + 2] = lz;
      out_xyz[o] = lx; out_xyz[o + 1] = ly; out_xyz[o + 2] = lz;
    }
    // no second barrier: wkd double-buffered on k&1
  }
}

// ---------------------------------------------------------------------------
// 32 nearest neighbors per sampled point — wave-per-query radix-rank select.
// One wave = one query; 64 pts/lane in registers; NO barriers, NO LDS.
// Downstream (per-sample MLP -> maxpool) is order-invariant, so only the SET
// of 32 smallest (sq, idx) pairs matters. Find V* = 32nd-smallest fkey(sq)
// by 32-step MSB binary search with ballot+popcount, then emit keys < V*
// (ballot compaction) and fill from keys == V* in ascending global idx —
// exactly jax.lax.top_k's value-then-index tie-break set.
// sq math bit-identical to reference model (fma chain, contract off).
// ---------------------------------------------------------------------------
__global__ __launch_bounds__(256) void topk_kernel(const float* __restrict__ xyz,
                                                   const float* __restrict__ nxyz,
                                                   int* __restrict__ gidx) {
  int wq = (blockIdx.x << 2) + (threadIdx.x >> 6);  // query id: b*1024 + p
  int lane = threadIdx.x & 63;
  int b = wq >> 10;
  const float* X = xyz + (size_t)b * NPTS * 3;
  float px = nxyz[wq * 3 + 0], py = nxyz[wq * 3 + 1], pz = nxyz[wq * 3 + 2];
  float n2p = (px * px + py * py) + pz * pz;

  unsigned ukey[64];
#pragma unroll
  for (int i = 0; i < 64; ++i) {
    int n = i * 64 + lane;
    float x = X[n * 3 + 0], y = X[n * 3 + 1], z = X[n * 3 + 2];
    float n2x = (x * x + y * y) + z * z;
    float dot = fmaf(pz, z, fmaf(py, y, px * x));
    float sq = (n2p + n2x) - 2.0f * dot;
    ukey[i] = fkey(sq);
  }

  // V* = max V with count(ukey < V) <= 31  == 32nd-smallest ukey value
  unsigned V = 0u;
  for (int bit = 31; bit >= 0; --bit) {
    unsigned cand = V | (1u << bit);
    int cnt = 0;
#pragma unroll
    for (int i = 0; i < 64; ++i)
      cnt += __popcll(__ballot(ukey[i] < cand));
    if (cnt <= 31) V = cand;
  }

  int* go = gidx + (size_t)wq * NSAMP;
  int base = 0;
#pragma unroll
  for (int i = 0; i < 64; ++i) {  // all strictly-below-threshold keys
    bool lt = ukey[i] < V;
    u64 m = __ballot(lt);
    if (lt) go[base + mbcnt64(m)] = i * 64 + lane;
    base += __popcll(m);
  }
#pragma unroll
  for (int i = 0; i < 64; ++i) {  // fill from ==V* by ascending idx
    bool eq = (ukey[i] == V);
    u64 m = __ballot(eq);
    if (eq) {
      int pos = base + mbcnt64(m);
      if (pos < NSAMP) go[pos] = i * 64 + lane;
    }
    base += __popcll(m);
  }
}

// ---------------------------------------------------------------------------
// Gather + 3-layer pointwise MLP (BN folded) + max over 32 samples.
// ---------------------------------------------------------------------------
__global__ __launch_bounds__(256) void mlp_kernel(
    const float* __restrict__ xyz, const float* __restrict__ featT,
    const float* __restrict__ nxyz, const int* __restrict__ gidx,
    const float* __restrict__ wt0, const float* __restrict__ bp0,
    const float* __restrict__ wt1, const float* __restrict__ bp1,
    const float* __restrict__ wt2, const float* __restrict__ bp2,
    float* __restrict__ outF) {
  __shared__ float XA[2][32][69];
  __shared__ float XB[2][32][69];
  int blk = blockIdx.x;
  int b = blk >> 9;
  int pb = (blk & 511) << 1;
  int t = threadIdx.x;

  for (int u = t; u < 2 * 32 * 67; u += 256) {
    int pt = u / (32 * 67);
    int r = u - pt * (32 * 67);
    int s = r / 67;
    int c = r - s * 67;
    int pp = pb + pt;
    int g = gidx[(size_t)(b * NPOINT + pp) * NSAMP + s];
    float val;
    if (c < 3)
      val = xyz[(size_t)(b * NPTS + g) * 3 + c] - nxyz[(size_t)(b * NPOINT + pp) * 3 + c];
    else
      val = featT[(size_t)(b * NPTS + g) * NCH + (c - 3)];
    XA[pt][s][c] = val;
  }
  __syncthreads();

  int w = __builtin_amdgcn_readfirstlane((int)(threadIdx.x >> 6));
  int l = t & 63;
  int s = l & 31;
  int pt = l >> 5;

  {  // L0: XA[*,*,0:67] -> XB[*,*,0:64]
    int ob = w * 16;
    float acc[16];
#pragma unroll
    for (int j = 0; j < 16; ++j) acc[j] = bp0[ob + j];
    for (int c = 0; c < 67; ++c) {
      float xv = XA[pt][s][c];
      const float* wr = wt0 + c * 64 + ob;
#pragma unroll
      for (int j = 0; j < 16; ++j) acc[j] = fmaf(xv, wr[j], acc[j]);
    }
#pragma unroll
    for (int j = 0; j < 16; ++j) XB[pt][s][ob + j] = fmaxf(acc[j], 0.0f);
  }
  __syncthreads();

  {  // L1: XB -> XA[*,*,0:64]
    int ob = w * 16;
    float acc[16];
#pragma unroll
    for (int j = 0; j < 16; ++j) acc[j] = bp1[ob + j];
    for (int c = 0; c < 64; ++c) {
      float xv = XB[pt][s][c];
      const float* wr = wt1 + c * 64 + ob;
#pragma unroll
      for (int j = 0; j < 16; ++j) acc[j] = fmaf(xv, wr[j], acc[j]);
    }
#pragma unroll
    for (int j = 0; j < 16; ++j) XA[pt][s][ob + j] = fmaxf(acc[j], 0.0f);
  }
  __syncthreads();

  {  // L2: XA -> regs; ReLU; butterfly max over the 32 s-lanes; write out
    int ob = w * 32;
    float acc[32];
#pragma unroll
    for (int j = 0; j < 32; ++j) acc[j] = bp2[ob + j];
    for (int c = 0; c < 64; ++c) {
      float xv = XA[pt][s][c];
      const float* wr = wt2 + c * 128 + ob;
#pragma unroll
      for (int j = 0; j < 32; ++j) acc[j] = fmaf(xv, wr[j], acc[j]);
    }
    float* orow = outF + (size_t)(b * NPOINT + pb + pt) * 128 + ob;
#pragma unroll
    for (int j = 0; j < 32; ++j) {
      float m = fmaxf(acc[j], 0.0f);
#pragma unroll
      for (int off = 16; off >= 1; off >>= 1) m = fmaxf(m, __shfl_xor(m, off, 64));
      if (s == 0) orow[j] = m;
    }
  }
}

// ---------------------------------------------------------------------------
extern "C" void kernel_launch(void* const* d_in, const int* in_sizes, int n_in,
                              void* d_out, int out_size, void* d_ws, size_t ws_size,
                              hipStream_t stream) {
  if (n_in < 20 || ws_size < WS_NEED) return;
  const float* xyz = (const float*)d_in[0];
  const float* feat = (const float*)d_in[1];
  const float* W0 = (const float*)d_in[2];
  const float* b0 = (const float*)d_in[3];
  const float* g0 = (const float*)d_in[4];
  const float* be0 = (const float*)d_in[5];
  const float* m0 = (const float*)d_in[6];
  const float* v0 = (const float*)d_in[7];
  const float* W1 = (const float*)d_in[8];
  const float* b1 = (const float*)d_in[9];
  const float* g1 = (const float*)d_in[10];
  const float* be1 = (const float*)d_in[11];
  const float* m1 = (const float*)d_in[12];
  const float* v1 = (const float*)d_in[13];
  const float* W2 = (const float*)d_in[14];
  const float* b2 = (const float*)d_in[15];
  const float* g2 = (const float*)d_in[16];
  const float* be2 = (const float*)d_in[17];
  const float* m2 = (const float*)d_in[18];
  const float* v2 = (const float*)d_in[19];

  char* ws = (char*)d_ws;
  float* featT = (float*)(ws + OFF_FEATT);
  float* nxyz = (float*)(ws + OFF_NEWXYZ);
  int* gidx = (int*)(ws + OFF_GIDX);
  float* wt0 = (float*)(ws + OFF_WT0);
  float* bp0 = (float*)(ws + OFF_BP0);
  float* wt1 = (float*)(ws + OFF_WT1);
  float* bp1 = (float*)(ws + OFF_BP1);
  float* wt2 = (float*)(ws + OFF_WT2);
  float* bp2 = (float*)(ws + OFF_BP2);

  float* out_xyz = (float*)d_out;                         // [16,1024,3]
  float* out_feat = (float*)d_out + NBATCH * NPOINT * 3;  // [16,1024,128]

  hipLaunchKernelGGL(prep_kernel, dim3(1), dim3(256), 0, stream,
                     W0, b0, g0, be0, m0, v0, W1, b1, g1, be1, m1, v1,
                     W2, b2, g2, be2, m2, v2, wt0, bp0, wt1, bp1, wt2, bp2);
  hipLaunchKernelGGL(transpose_kernel, dim3(NPTS / 32, NCH / 32, NBATCH), dim3(32, 8), 0, stream,
                     feat, featT);
  hipLaunchKernelGGL(fps_kernel, dim3(NBATCH), dim3(256), 0, stream, xyz, nxyz, out_xyz);
  hipLaunchKernelGGL(topk_kernel, dim3(NBATCH * NPOINT / 4), dim3(256), 0, stream,
                     xyz, nxyz, gidx);
  hipLaunchKernelGGL(mlp_kernel, dim3(NBATCH * NPOINT / 2), dim3(256), 0, stream,
                     xyz, featT, nxyz, gidx, wt0, bp0, wt1, bp1, wt2, bp2, out_feat);
}

// Round 9
// 1120.831 us; speedup vs baseline: 1.8150x; 1.0624x over previous
//
#include <hip/hip_runtime.h>
#include <stdint.h>

#pragma clang fp contract(off)

typedef unsigned long long u64;
typedef float __attribute__((ext_vector_type(2))) f32x2;

#define NBATCH 16
#define NPTS   4096
#define NCH    64
#define NPOINT 1024
#define NSAMP  32

// ---- workspace byte offsets ----
#define OFF_FEATT   0u          // 16*4096*64*4 = 16777216
#define OFF_NEWXYZ  16777216u   // 16*1024*3*4 = 196608
#define OFF_GIDX    16973824u   // 16*1024*32*4 = 2097152
#define OFF_WT0     19070976u   // 67*64*4 = 17152
#define OFF_BP0     19088128u   // 64*4 (pad 256)
#define OFF_WT1     19088384u   // 64*64*4 = 16384
#define OFF_BP1     19104768u   // pad 256
#define OFF_WT2     19105024u   // 64*128*4 = 32768
#define OFF_BP2     19137792u   // pad 512
#define WS_NEED     19138304u

// Monotone map: float bits -> unsigned preserving total order (neg < pos).
__device__ __forceinline__ unsigned fkey(float f) {
  unsigned b = __float_as_uint(f);
  unsigned mask = ((unsigned)((int)b >> 31)) | 0x80000000u;
  return b ^ mask;
}

__device__ __forceinline__ double mkkey(float v, unsigned lo) {
  // key = (bits(v) << 32) | lo, viewed as double. v in [0, 1e10] -> positive
  // double, never NaN/Inf -> u64 order == f64 order -> fmax == u64 max.
  return __longlong_as_double((long long)(((u64)__float_as_uint(v) << 32) | lo));
}

__device__ __forceinline__ int mbcnt64(u64 m) {
  int c = __builtin_amdgcn_mbcnt_lo((unsigned)m, 0);
  return __builtin_amdgcn_mbcnt_hi((unsigned)(m >> 32), c);
}

// ---------------------------------------------------------------------------
// Fold BN (eval) into conv weights/bias; transpose W to [c][o].
// ---------------------------------------------------------------------------
__global__ __launch_bounds__(256) void prep_kernel(
    const float* __restrict__ W0, const float* __restrict__ b0, const float* __restrict__ g0,
    const float* __restrict__ be0, const float* __restrict__ m0, const float* __restrict__ v0,
    const float* __restrict__ W1, const float* __restrict__ b1, const float* __restrict__ g1,
    const float* __restrict__ be1, const float* __restrict__ m1, const float* __restrict__ v1,
    const float* __restrict__ W2, const float* __restrict__ b2, const float* __restrict__ g2,
    const float* __restrict__ be2, const float* __restrict__ m2, const float* __restrict__ v2,
    float* __restrict__ wt0, float* __restrict__ bp0,
    float* __restrict__ wt1, float* __restrict__ bp1,
    float* __restrict__ wt2, float* __restrict__ bp2) {
  int t = threadIdx.x;
  for (int i = t; i < 64 * 67; i += 256) {
    int o = i / 67, c = i % 67;
    float s = g0[o] / sqrtf(v0[o] + 1e-5f);
    wt0[c * 64 + o] = W0[o * 67 + c] * s;
  }
  for (int o = t; o < 64; o += 256) {
    float s = g0[o] / sqrtf(v0[o] + 1e-5f);
    bp0[o] = (b0[o] - m0[o]) * s + be0[o];
  }
  for (int i = t; i < 64 * 64; i += 256) {
    int o = i / 64, c = i % 64;
    float s = g1[o] / sqrtf(v1[o] + 1e-5f);
    wt1[c * 64 + o] = W1[o * 64 + c] * s;
  }
  for (int o = t; o < 64; o += 256) {
    float s = g1[o] / sqrtf(v1[o] + 1e-5f);
    bp1[o] = (b1[o] - m1[o]) * s + be1[o];
  }
  for (int i = t; i < 128 * 64; i += 256) {
    int o = i / 64, c = i % 64;
    float s = g2[o] / sqrtf(v2[o] + 1e-5f);
    wt2[c * 128 + o] = W2[o * 64 + c] * s;
  }
  for (int o = t; o < 128; o += 256) {
    float s = g2[o] / sqrtf(v2[o] + 1e-5f);
    bp2[o] = (b2[o] - m2[o]) * s + be2[o];
  }
}

// ---------------------------------------------------------------------------
// features [B,C,N] -> featT [B,N,C]  (tiled 32x32 transpose)
// ---------------------------------------------------------------------------
__global__ __launch_bounds__(256) void transpose_kernel(const float* __restrict__ feat,
                                                        float* __restrict__ featT) {
  __shared__ float tile[32][33];
  int b = blockIdx.z;
  int n0 = blockIdx.x * 32;
  int c0 = blockIdx.y * 32;
  int tx = threadIdx.x, ty = threadIdx.y;  // 32 x 8
#pragma unroll
  for (int j = 0; j < 4; ++j)
    tile[ty + 8 * j][tx] = feat[b * (NCH * NPTS) + (c0 + ty + 8 * j) * NPTS + n0 + tx];
  __syncthreads();
#pragma unroll
  for (int j = 0; j < 4; ++j)
    featT[b * (NPTS * NCH) + (size_t)(n0 + ty + 8 * j) * NCH + c0 + tx] = tile[tx][ty + 8 * j];
}

// ---------------------------------------------------------------------------
// Exact farthest-point sampling. One block per batch, 256 threads x 16 pts
// held as 8x f32x2 -> packed v_pk_{sub,mul,add,min}_f32 distance update
// (per-component fp ops identical to scalar; order (dx^2+dy^2)+dz^2 kept).
// f64-key argmax (R4/R6 scheme) unchanged. Winner coords buffered in LDS by
// t0 each iter; coalesced global write in epilogue (removes per-iter global
// stores from the barrier-synced critical path).
// ---------------------------------------------------------------------------
#define DPP_MAXSTEP(CTRL)                                                                          \
  do {                                                                                             \
    u64 kb_ = (u64)__double_as_longlong(key);                                                      \
    unsigned lo_ = (unsigned)kb_, hi_ = (unsigned)(kb_ >> 32);                                     \
    unsigned slo = (unsigned)__builtin_amdgcn_update_dpp((int)lo_, (int)lo_, CTRL, 0xF, 0xF, false); \
    unsigned shi = (unsigned)__builtin_amdgcn_update_dpp((int)hi_, (int)hi_, CTRL, 0xF, 0xF, false); \
    key = fmax(key, __longlong_as_double((long long)(((u64)shi << 32) | slo)));                    \
  } while (0)

__global__ __launch_bounds__(256) void fps_kernel(const float* __restrict__ xyz,
                                                  float* __restrict__ nxyz,
                                                  float* __restrict__ out_xyz) {
  __shared__ float sx[NPTS], sy[NPTS], sz[NPTS];
  __shared__ float outc[NPOINT][3];
  __shared__ double wkd[2][4];
  int b = blockIdx.x;
  int t = threadIdx.x;
  const float* X = xyz + (size_t)b * NPTS * 3;

  f32x2 qx[8], qy[8], qz[8], d2[8];
  unsigned nio[16];  // ~global_idx, loop-invariant key low words
#pragma unroll
  for (int i = 0; i < 8; ++i) {
    int p0 = t + 256 * (2 * i);
    int p1 = t + 256 * (2 * i + 1);
    float x0 = X[p0 * 3 + 0], y0 = X[p0 * 3 + 1], z0 = X[p0 * 3 + 2];
    float x1 = X[p1 * 3 + 0], y1 = X[p1 * 3 + 1], z1 = X[p1 * 3 + 2];
    qx[i].x = x0; qx[i].y = x1;
    qy[i].x = y0; qy[i].y = y1;
    qz[i].x = z0; qz[i].y = z1;
    sx[p0] = x0; sy[p0] = y0; sz[p0] = z0;
    sx[p1] = x1; sy[p1] = y1; sz[p1] = z1;
    d2[i].x = 1e10f; d2[i].y = 1e10f;
    nio[2 * i] = ~(unsigned)p0;
    nio[2 * i + 1] = ~(unsigned)p1;
  }
  __syncthreads();

  float lx = sx[0], ly = sy[0], lz = sz[0];
  if (t == 0) { outc[0][0] = lx; outc[0][1] = ly; outc[0][2] = lz; }

  for (int k = 1; k < NPOINT; ++k) {
    f32x2 vlx; vlx.x = lx; vlx.y = lx;
    f32x2 vly; vly.x = ly; vly.y = ly;
    f32x2 vlz; vlz.x = lz; vlz.y = lz;
    // distance update: contract(off), exact per-component order (dx^2+dy^2)+dz^2
#pragma unroll
    for (int i = 0; i < 8; ++i) {
      f32x2 dx = qx[i] - vlx, dy = qy[i] - vly, dz = qz[i] - vlz;
      f32x2 dist = (dx * dx + dy * dy) + dz * dz;
      d2[i] = __builtin_elementwise_min(d2[i], dist);
    }
    // 16 keys -> 15 v_max_f64 tree
    double k0 = fmax(mkkey(d2[0].x, nio[0]), mkkey(d2[0].y, nio[1]));
    double k1 = fmax(mkkey(d2[1].x, nio[2]), mkkey(d2[1].y, nio[3]));
    double k2 = fmax(mkkey(d2[2].x, nio[4]), mkkey(d2[2].y, nio[5]));
    double k3 = fmax(mkkey(d2[3].x, nio[6]), mkkey(d2[3].y, nio[7]));
    double k4 = fmax(mkkey(d2[4].x, nio[8]), mkkey(d2[4].y, nio[9]));
    double k5 = fmax(mkkey(d2[5].x, nio[10]), mkkey(d2[5].y, nio[11]));
    double k6 = fmax(mkkey(d2[6].x, nio[12]), mkkey(d2[6].y, nio[13]));
    double k7 = fmax(mkkey(d2[7].x, nio[14]), mkkey(d2[7].y, nio[15]));
    k0 = fmax(k0, k1); k2 = fmax(k2, k3); k4 = fmax(k4, k5); k6 = fmax(k6, k7);
    k0 = fmax(k0, k2); k4 = fmax(k4, k6);
    double key = fmax(k0, k4);

    // wave64 max-reduce; lane 63 ends with the wave max
    DPP_MAXSTEP(0xB1);   // quad_perm xor1
    DPP_MAXSTEP(0x4E);   // quad_perm xor2
    DPP_MAXSTEP(0x124);  // row_ror:4
    DPP_MAXSTEP(0x128);  // row_ror:8
    DPP_MAXSTEP(0x142);  // row_bcast15
    DPP_MAXSTEP(0x143);  // row_bcast31

    int kb = k & 1;
    if ((t & 63) == 63) wkd[kb][t >> 6] = key;
    __syncthreads();
    double w0 = wkd[kb][0], w1 = wkd[kb][1], w2 = wkd[kb][2], w3 = wkd[kb][3];
    w0 = fmax(w0, w1); w2 = fmax(w2, w3);
    w0 = fmax(w0, w2);
    int last = (int)(~(unsigned)(u64)__double_as_longlong(w0));
    lx = sx[last]; ly = sy[last]; lz = sz[last];  // broadcast LDS reads
    if (t == 0) { outc[k][0] = lx; outc[k][1] = ly; outc[k][2] = lz; }
    // no second barrier: wkd double-buffered on k&1
  }
  __syncthreads();
  for (int p = t; p < NPOINT; p += 256) {
    float x = outc[p][0], y = outc[p][1], z = outc[p][2];
    int o = (b * NPOINT + p) * 3;
    nxyz[o] = x; nxyz[o + 1] = y; nxyz[o + 2] = z;
    out_xyz[o] = x; out_xyz[o + 1] = y; out_xyz[o + 2] = z;
  }
}

// ---------------------------------------------------------------------------
// 32 nearest neighbors per sampled point — wave-per-query radix-rank select.
// (R8: measured as part of the -210us total gain; registers-only, no LDS.)
// ---------------------------------------------------------------------------
__global__ __launch_bounds__(256) void topk_kernel(const float* __restrict__ xyz,
                                                   const float* __restrict__ nxyz,
                                                   int* __restrict__ gidx) {
  int wq = (blockIdx.x << 2) + (threadIdx.x >> 6);  // query id: b*1024 + p
  int lane = threadIdx.x & 63;
  int b = wq >> 10;
  const float* X = xyz + (size_t)b * NPTS * 3;
  float px = nxyz[wq * 3 + 0], py = nxyz[wq * 3 + 1], pz = nxyz[wq * 3 + 2];
  float n2p = (px * px + py * py) + pz * pz;

  unsigned ukey[64];
#pragma unroll
  for (int i = 0; i < 64; ++i) {
    int n = i * 64 + lane;
    float x = X[n * 3 + 0], y = X[n * 3 + 1], z = X[n * 3 + 2];
    float n2x = (x * x + y * y) + z * z;
    float dot = fmaf(pz, z, fmaf(py, y, px * x));
    float sq = (n2p + n2x) - 2.0f * dot;
    ukey[i] = fkey(sq);
  }

  // V* = max V with count(ukey < V) <= 31  == 32nd-smallest ukey value
  unsigned V = 0u;
  for (int bit = 31; bit >= 0; --bit) {
    unsigned cand = V | (1u << bit);
    int cnt = 0;
#pragma unroll
    for (int i = 0; i < 64; ++i)
      cnt += __popcll(__ballot(ukey[i] < cand));
    if (cnt <= 31) V = cand;
  }

  int* go = gidx + (size_t)wq * NSAMP;
  int base = 0;
#pragma unroll
  for (int i = 0; i < 64; ++i) {  // all strictly-below-threshold keys
    bool lt = ukey[i] < V;
    u64 m = __ballot(lt);
    if (lt) go[base + mbcnt64(m)] = i * 64 + lane;
    base += __popcll(m);
  }
#pragma unroll
  for (int i = 0; i < 64; ++i) {  // fill from ==V* by ascending idx
    bool eq = (ukey[i] == V);
    u64 m = __ballot(eq);
    if (eq) {
      int pos = base + mbcnt64(m);
      if (pos < NSAMP) go[pos] = i * 64 + lane;
    }
    base += __popcll(m);
  }
}

// ---------------------------------------------------------------------------
// Gather + 3-layer pointwise MLP (BN folded) + max over 32 samples.
// Packed f32x2 accumulators + weights -> v_pk_fma_f32 (2x fp32 FMA rate).
// contract(fast) scoped to this kernel only (MLP needs ~1e-2 accuracy, not
// bit-exactness; selection kernels above stay contract(off)).
// ---------------------------------------------------------------------------
__global__ __launch_bounds__(256) void mlp_kernel(
    const float* __restrict__ xyz, const float* __restrict__ featT,
    const float* __restrict__ nxyz, const int* __restrict__ gidx,
    const float* __restrict__ wt0, const float* __restrict__ bp0,
    const float* __restrict__ wt1, const float* __restrict__ bp1,
    const float* __restrict__ wt2, const float* __restrict__ bp2,
    float* __restrict__ outF) {
#pragma clang fp contract(fast)
  __shared__ float XA[2][32][69];
  __shared__ float XB[2][32][69];
  int blk = blockIdx.x;
  int b = blk >> 9;
  int pb = (blk & 511) << 1;
  int t = threadIdx.x;

  for (int u = t; u < 2 * 32 * 67; u += 256) {
    int pt = u / (32 * 67);
    int r = u - pt * (32 * 67);
    int s = r / 67;
    int c = r - s * 67;
    int pp = pb + pt;
    int g = gidx[(size_t)(b * NPOINT + pp) * NSAMP + s];
    float val;
    if (c < 3)
      val = xyz[(size_t)(b * NPTS + g) * 3 + c] - nxyz[(size_t)(b * NPOINT + pp) * 3 + c];
    else
      val = featT[(size_t)(b * NPTS + g) * NCH + (c - 3)];
    XA[pt][s][c] = val;
  }
  __syncthreads();

  int w = __builtin_amdgcn_readfirstlane((int)(threadIdx.x >> 6));
  int l = t & 63;
  int s = l & 31;
  int pt = l >> 5;

  {  // L0: XA[*,*,0:67] -> XB[*,*,0:64]
    int ob = w * 16;
    f32x2 acc[8];
    const f32x2* bp2v = (const f32x2*)(bp0 + ob);
#pragma unroll
    for (int j = 0; j < 8; ++j) acc[j] = bp2v[j];
    for (int c = 0; c < 67; ++c) {
      float xv = XA[pt][s][c];
      f32x2 xv2; xv2.x = xv; xv2.y = xv;
      const f32x2* wr2 = (const f32x2*)(wt0 + c * 64 + ob);
#pragma unroll
      for (int j = 0; j < 8; ++j) acc[j] = acc[j] + xv2 * wr2[j];  // v_pk_fma_f32
    }
#pragma unroll
    for (int j = 0; j < 8; ++j) {
      XB[pt][s][ob + 2 * j] = fmaxf(acc[j].x, 0.0f);
      XB[pt][s][ob + 2 * j + 1] = fmaxf(acc[j].y, 0.0f);
    }
  }
  __syncthreads();

  {  // L1: XB -> XA[*,*,0:64]
    int ob = w * 16;
    f32x2 acc[8];
    const f32x2* bp2v = (const f32x2*)(bp1 + ob);
#pragma unroll
    for (int j = 0; j < 8; ++j) acc[j] = bp2v[j];
    for (int c = 0; c < 64; ++c) {
      float xv = XB[pt][s][c];
      f32x2 xv2; xv2.x = xv; xv2.y = xv;
      const f32x2* wr2 = (const f32x2*)(wt1 + c * 64 + ob);
#pragma unroll
      for (int j = 0; j < 8; ++j) acc[j] = acc[j] + xv2 * wr2[j];
    }
#pragma unroll
    for (int j = 0; j < 8; ++j) {
      XA[pt][s][ob + 2 * j] = fmaxf(acc[j].x, 0.0f);
      XA[pt][s][ob + 2 * j + 1] = fmaxf(acc[j].y, 0.0f);
    }
  }
  __syncthreads();

  {  // L2: XA -> regs; ReLU; butterfly max over the 32 s-lanes; write out
    int ob = w * 32;
    f32x2 acc[16];
    const f32x2* bp2v = (const f32x2*)(bp2 + ob);
#pragma unroll
    for (int j = 0; j < 16; ++j) acc[j] = bp2v[j];
    for (int c = 0; c < 64; ++c) {
      float xv = XA[pt][s][c];
      f32x2 xv2; xv2.x = xv; xv2.y = xv;
      const f32x2* wr2 = (const f32x2*)(wt2 + c * 128 + ob);
#pragma unroll
      for (int j = 0; j < 16; ++j) acc[j] = acc[j] + xv2 * wr2[j];
    }
    float* orow = outF + (size_t)(b * NPOINT + pb + pt) * 128 + ob;
#pragma unroll
    for (int j = 0; j < 32; ++j) {
      float v = (j & 1) ? acc[j >> 1].y : acc[j >> 1].x;
      float m = fmaxf(v, 0.0f);
#pragma unroll
      for (int off = 16; off >= 1; off >>= 1) m = fmaxf(m, __shfl_xor(m, off, 64));
      if (s == 0) orow[j] = m;
    }
  }
}

// ---------------------------------------------------------------------------
extern "C" void kernel_launch(void* const* d_in, const int* in_sizes, int n_in,
                              void* d_out, int out_size, void* d_ws, size_t ws_size,
                              hipStream_t stream) {
  if (n_in < 20 || ws_size < WS_NEED) return;
  const float* xyz = (const float*)d_in[0];
  const float* feat = (const float*)d_in[1];
  const float* W0 = (const float*)d_in[2];
  const float* b0 = (const float*)d_in[3];
  const float* g0 = (const float*)d_in[4];
  const float* be0 = (const float*)d_in[5];
  const float* m0 = (const float*)d_in[6];
  const float* v0 = (const float*)d_in[7];
  const float* W1 = (const float*)d_in[8];
  const float* b1 = (const float*)d_in[9];
  const float* g1 = (const float*)d_in[10];
  const float* be1 = (const float*)d_in[11];
  const float* m1 = (const float*)d_in[12];
  const float* v1 = (const float*)d_in[13];
  const float* W2 = (const float*)d_in[14];
  const float* b2 = (const float*)d_in[15];
  const float* g2 = (const float*)d_in[16];
  const float* be2 = (const float*)d_in[17];
  const float* m2 = (const float*)d_in[18];
  const float* v2 = (const float*)d_in[19];

  char* ws = (char*)d_ws;
  float* featT = (float*)(ws + OFF_FEATT);
  float* nxyz = (float*)(ws + OFF_NEWXYZ);
  int* gidx = (int*)(ws + OFF_GIDX);
  float* wt0 = (float*)(ws + OFF_WT0);
  float* bp0 = (float*)(ws + OFF_BP0);
  float* wt1 = (float*)(ws + OFF_WT1);
  float* bp1 = (float*)(ws + OFF_BP1);
  float* wt2 = (float*)(ws + OFF_WT2);
  float* bp2 = (float*)(ws + OFF_BP2);

  float* out_xyz = (float*)d_out;                         // [16,1024,3]
  float* out_feat = (float*)d_out + NBATCH * NPOINT * 3;  // [16,1024,128]

  hipLaunchKernelGGL(prep_kernel, dim3(1), dim3(256), 0, stream,
                     W0, b0, g0, be0, m0, v0, W1, b1, g1, be1, m1, v1,
                     W2, b2, g2, be2, m2, v2, wt0, bp0, wt1, bp1, wt2, bp2);
  hipLaunchKernelGGL(transpose_kernel, dim3(NPTS / 32, NCH / 32, NBATCH), dim3(32, 8), 0, stream,
                     feat, featT);
  hipLaunchKernelGGL(fps_kernel, dim3(NBATCH), dim3(256), 0, stream, xyz, nxyz, out_xyz);
  hipLaunchKernelGGL(topk_kernel, dim3(NBATCH * NPOINT / 4), dim3(256), 0, stream,
                     xyz, nxyz, gidx);
  hipLaunchKernelGGL(mlp_kernel, dim3(NBATCH * NPOINT / 2), dim3(256), 0, stream,
                     xyz, featT, nxyz, gidx, wt0, bp0, wt1, bp1, wt2, bp2, out_feat);
}